// Round 1
// baseline (5550.723 us; speedup 1.0000x reference)
//
#include <hip/hip_runtime.h>
#include <math.h>

#define LSEQ 1024
#define DMODEL 768
#define NHEAD 8
#define HDIM 96
#define DI_ 1536
#define NST 16
#define DTR_ 48
#define FF_ 3072

// ---------------------------------------------------------------------------
// Generic fp32 GEMM: C[m,n] = act( A[m,:] . W[n,:] + bias[n] )  (+ residual / *=C)
// A is (2048 x lda) row-major, rows indexed as b*L + l with optional l-flip.
// W is (Ncols x Kd) row-major (i.e. computes A @ W^T).
// C written at C[row*ldc + colOff + n], row optionally l-flipped.
// act: 0=none, 1=softplus, 2=silu.  mulC: C *= v instead of C = v.
// ---------------------------------------------------------------------------
__global__ __launch_bounds__(256) void gemm_f32(
    const float* __restrict__ A, int lda, int flipA,
    const float* __restrict__ W,
    const float* __restrict__ bias,
    const float* __restrict__ residual,
    float* __restrict__ C, int ldc, int colOff, int flipC,
    int Ncols, int Kd, int act, int mulC)
{
  __shared__ float As[16][65];
  __shared__ float Bs[16][65];
  const int row0 = blockIdx.y * 64, col0 = blockIdx.x * 64;
  const int tid = threadIdx.x;
  const int tx = tid & 15, ty = tid >> 4;
  float acc[4][4] = {};
  const int lm = tid >> 2;
  const int lk = (tid & 3) << 2;
  int gmL = row0 + lm;
  int bbL = gmL >> 10, llL = gmL & 1023;
  if (flipA) llL = LSEQ - 1 - llL;
  const float* arow = A + (size_t)(bbL * LSEQ + llL) * lda;
  int gnL = col0 + lm;
  const bool wvalid = (gnL < Ncols);
  const float* wrow = W + (size_t)(wvalid ? gnL : 0) * Kd;

  for (int k0 = 0; k0 < Kd; k0 += 16) {
    #pragma unroll
    for (int u = 0; u < 4; ++u) {
      int kk = k0 + lk + u;
      bool kin = (kk < Kd);
      As[lk + u][lm] = kin ? arow[kk] : 0.f;
      Bs[lk + u][lm] = (kin && wvalid) ? wrow[kk] : 0.f;
    }
    __syncthreads();
    #pragma unroll
    for (int kk = 0; kk < 16; ++kk) {
      float a[4], bv[4];
      #pragma unroll
      for (int i = 0; i < 4; ++i) a[i] = As[kk][(ty << 2) + i];
      #pragma unroll
      for (int j = 0; j < 4; ++j) bv[j] = Bs[kk][(tx << 2) + j];
      #pragma unroll
      for (int i = 0; i < 4; ++i)
        #pragma unroll
        for (int j = 0; j < 4; ++j)
          acc[i][j] = fmaf(a[i], bv[j], acc[i][j]);
    }
    __syncthreads();
  }

  #pragma unroll
  for (int i = 0; i < 4; ++i) {
    int gm = row0 + (ty << 2) + i;
    int bb = gm >> 10, ll = gm & 1023;
    if (flipC) ll = LSEQ - 1 - ll;
    size_t base = (size_t)(bb * LSEQ + ll) * ldc + colOff;
    #pragma unroll
    for (int j = 0; j < 4; ++j) {
      int gn = col0 + (tx << 2) + j;
      if (gn >= Ncols) continue;
      float v = acc[i][j];
      if (bias) v += bias[gn];
      if (act == 1) v = fmaxf(v, 0.f) + log1pf(__expf(-fabsf(v)));   // softplus
      else if (act == 2) v = v / (1.f + __expf(-v));                 // silu
      size_t idx = base + gn;
      if (mulC) C[idx] *= v;
      else if (residual) C[idx] = residual[idx] + v;
      else C[idx] = v;
    }
  }
}

// ---------------------------------------------------------------------------
// Attention (fp32, scores in LDS). One block = one (b,h) x 8 query rows.
// qkv layout: (B*L) x 2304, q=[0:768), k=[768:1536), v=[1536:2304).
// ---------------------------------------------------------------------------
#define TQ 8
__global__ __launch_bounds__(256) void attn_f32(const float* __restrict__ qkv,
                                                float* __restrict__ o)
{
  __shared__ float S[TQ][LSEQ + 1];
  __shared__ float Q[TQ][HDIM + 4];
  __shared__ float red[TQ][32];
  __shared__ float rowstat[TQ];
  const int bh = blockIdx.y;
  const int b_ = bh >> 3, h = bh & 7;
  const int q0 = blockIdx.x * TQ;
  const int tid = threadIdx.x;

  for (int i = tid; i < TQ * HDIM; i += 256) {
    int r = i / HDIM, dd = i - r * HDIM;
    Q[r][dd] = qkv[((size_t)(b_ * LSEQ) + q0 + r) * 2304 + h * HDIM + dd];
  }
  __syncthreads();

  const int r = tid & 7, jc = tid >> 3;   // 8 rows x 32 key-columns
  const float scale = 0.1020620726159658f; // 1/sqrt(96)

  for (int t = 0; t < LSEQ / 32; ++t) {
    int j = jc + 32 * t;
    const float* kp = qkv + ((size_t)(b_ * LSEQ) + j) * 2304 + DMODEL + h * HDIM;
    float s = 0.f;
    #pragma unroll 8
    for (int dd = 0; dd < HDIM; ++dd) s = fmaf(Q[r][dd], kp[dd], s);
    S[r][j] = s * scale;
  }
  __syncthreads();

  float pm = -1e30f;
  for (int t = 0; t < 32; ++t) pm = fmaxf(pm, S[r][jc + 32 * t]);
  red[r][jc] = pm;
  __syncthreads();
  if (tid < TQ) {
    float m = -1e30f;
    for (int u = 0; u < 32; ++u) m = fmaxf(m, red[tid][u]);
    rowstat[tid] = m;
  }
  __syncthreads();
  float m = rowstat[r];
  float ps = 0.f;
  for (int t = 0; t < 32; ++t) {
    int j = jc + 32 * t;
    float e = __expf(S[r][j] - m);
    S[r][j] = e;
    ps += e;
  }
  red[r][jc] = ps;
  __syncthreads();
  if (tid < TQ) {
    float ssum = 0.f;
    for (int u = 0; u < 32; ++u) ssum += red[tid][u];
    rowstat[tid] = ssum;
  }
  __syncthreads();
  const float inv = 1.f / rowstat[r];

  // phase 3: d = jc + 32*u, u<3
  float acc0 = 0.f, acc1 = 0.f, acc2 = 0.f;
  for (int j = 0; j < LSEQ; ++j) {
    float p = S[r][j];
    const float* vp = qkv + ((size_t)(b_ * LSEQ) + j) * 2304 + 2 * DMODEL + h * HDIM + jc;
    acc0 = fmaf(p, vp[0], acc0);
    acc1 = fmaf(p, vp[32], acc1);
    acc2 = fmaf(p, vp[64], acc2);
  }
  float* op = o + ((size_t)(b_ * LSEQ) + q0 + r) * DMODEL + h * HDIM + jc;
  op[0]  = acc0 * inv;
  op[32] = acc1 * inv;
  op[64] = acc2 * inv;
}

// ---------------------------------------------------------------------------
// GLCE convs: grouped conv1d (3 in-ch per out-ch), kernels 3/5/7, exact gelu.
// Output loc[b,l,c], c<256: conv3 ch c, 256..511: conv5, 512..767: conv7.
// ---------------------------------------------------------------------------
__global__ __launch_bounds__(256) void glce_conv(
    const float* __restrict__ x,
    const float* __restrict__ w3, const float* __restrict__ b3,
    const float* __restrict__ w5, const float* __restrict__ b5,
    const float* __restrict__ w7, const float* __restrict__ b7,
    float* __restrict__ loc)
{
  int idx = blockIdx.x * 256 + threadIdx.x;
  int c = idx % DMODEL;
  int bl = idx / DMODEL;
  int l = bl & 1023, b_ = bl >> 10;
  int cs = c >> 8, ch = c & 255;
  const float* wp; float bias; int kt, pad;
  if (cs == 0)      { wp = w3 + ch * 9;  bias = b3[ch]; kt = 3; pad = 1; }
  else if (cs == 1) { wp = w5 + ch * 15; bias = b5[ch]; kt = 5; pad = 2; }
  else              { wp = w7 + ch * 21; bias = b7[ch]; kt = 7; pad = 3; }
  float acc = bias;
  const float* xb = x + (size_t)(b_ * LSEQ) * DMODEL;
  for (int i = 0; i < 3; ++i) {
    int d = 3 * ch + i;
    for (int t = 0; t < kt; ++t) {
      int ls = l - pad + t;
      if (ls >= 0 && ls < LSEQ)
        acc = fmaf(xb[(size_t)ls * DMODEL + d], wp[i * kt + t], acc);
    }
  }
  loc[idx] = 0.5f * acc * (1.f + erff(acc * 0.7071067811865475f));
}

// ---------------------------------------------------------------------------
// Mamba depthwise causal conv (K=4, pad left 3) + silu. xi is XIZ[:, :1536].
// ---------------------------------------------------------------------------
__global__ __launch_bounds__(256) void mamba_conv_f32(
    const float* __restrict__ xiz, const float* __restrict__ cw,
    const float* __restrict__ cb, float* __restrict__ xc)
{
  int idx = blockIdx.x * 256 + threadIdx.x;
  int d = idx % DI_;
  int bl = idx / DI_;
  int l = bl & 1023, b_ = bl >> 10;
  const float* w = cw + d * 4;
  float acc = cb[d];
  #pragma unroll
  for (int t = 0; t < 4; ++t) {
    int ls = l - 3 + t;
    if (ls >= 0)
      acc = fmaf(xiz[((size_t)(b_ * LSEQ + ls)) * 3072 + d], w[t], acc);
  }
  xc[idx] = acc / (1.f + __expf(-acc));
}

// ---------------------------------------------------------------------------
// Selective scan: one thread per (b,d), 16 states in registers.
// dbc: (B*L) x 80 (dt | B | C). Also fuses y = ys + xc*D and y *= silu(z).
// ---------------------------------------------------------------------------
__global__ __launch_bounds__(256) void mamba_scan_f32(
    const float* __restrict__ dbc, const float* __restrict__ delta,
    const float* __restrict__ xc, const float* __restrict__ xiz,
    const float* __restrict__ A_log, const float* __restrict__ Dp,
    float* __restrict__ yg)
{
  int b_ = blockIdx.x / 6;
  int d = (blockIdx.x % 6) * 256 + threadIdx.x;
  float a2[16];
  #pragma unroll
  for (int n = 0; n < 16; ++n)
    a2[n] = -__expf(A_log[d * 16 + n]) * 1.4426950408889634f;  // A * log2(e)
  const float dv = Dp[d];
  float h[16];
  #pragma unroll
  for (int n = 0; n < 16; ++n) h[n] = 0.f;
  __shared__ float bc[64][32];
  const size_t rowb = (size_t)b_ * LSEQ;

  for (int l0 = 0; l0 < LSEQ; l0 += 64) {
    __syncthreads();
    for (int i = threadIdx.x; i < 64 * 32; i += 256) {
      int lc = i >> 5, col = i & 31;
      bc[lc][col] = dbc[(rowb + l0 + lc) * 80 + 48 + col];
    }
    __syncthreads();
    for (int lc = 0; lc < 64; ++lc) {
      size_t row = rowb + l0 + lc;
      float dl = delta[row * 1536 + d];
      float xv = xc[row * 1536 + d];
      float zv = xiz[row * 3072 + 1536 + d];
      float dx = dl * xv;
      float y = xv * dv;
      #pragma unroll
      for (int n = 0; n < 16; ++n) {
        float dA = exp2f(dl * a2[n]);
        h[n] = fmaf(dA, h[n], dx * bc[lc][n]);
        y = fmaf(h[n], bc[lc][16 + n], y);
      }
      float sg = 1.f / (1.f + __expf(-zv));
      yg[row * 1536 + d] = y * (zv * sg);
    }
  }
}

// ---------------------------------------------------------------------------
// LayerNorm over last dim (768). One wave per row.
// ---------------------------------------------------------------------------
__global__ __launch_bounds__(256) void ln_f32(
    const float* __restrict__ in, const float* __restrict__ g,
    const float* __restrict__ b, float* __restrict__ out)
{
  int row = blockIdx.x * 4 + (threadIdx.x >> 6);
  int lane = threadIdx.x & 63;
  const float* xr = in + (size_t)row * DMODEL;
  float v[12];
  float s = 0.f, s2 = 0.f;
  #pragma unroll
  for (int i = 0; i < 12; ++i) {
    float t = xr[i * 64 + lane];
    v[i] = t; s += t; s2 = fmaf(t, t, s2);
  }
  #pragma unroll
  for (int off = 1; off < 64; off <<= 1) {
    s += __shfl_xor(s, off);
    s2 += __shfl_xor(s2, off);
  }
  float mean = s * (1.f / 768.f);
  float var = s2 * (1.f / 768.f) - mean * mean;
  float inv = rsqrtf(var + 1e-5f);
  float* orow = out + (size_t)row * DMODEL;
  #pragma unroll
  for (int i = 0; i < 12; ++i) {
    int c = i * 64 + lane;
    orow[c] = (v[i] - mean) * inv * g[c] + b[c];
  }
}

__global__ __launch_bounds__(256) void add3_f32(
    const float* __restrict__ a, const float* __restrict__ b,
    const float* __restrict__ c, float* __restrict__ o)
{
  int i = blockIdx.x * 256 + threadIdx.x;
  o[i] = a[i] + b[i] + c[i];
}

// ---------------------------------------------------------------------------
extern "C" void kernel_launch(void* const* d_in, const int* in_sizes, int n_in,
                              void* d_out, int out_size, void* d_ws, size_t ws_size,
                              hipStream_t stream)
{
  (void)in_sizes; (void)n_in; (void)out_size; (void)ws_size;
  const float* x         = (const float*)d_in[0];
  const float* qkv_w     = (const float*)d_in[1];
  const float* qkv_b     = (const float*)d_in[2];
  const float* att_out_w = (const float*)d_in[3];
  const float* att_out_b = (const float*)d_in[4];
  const float* conv3_w   = (const float*)d_in[5];
  const float* conv3_b   = (const float*)d_in[6];
  const float* conv5_w   = (const float*)d_in[7];
  const float* conv5_b   = (const float*)d_in[8];
  const float* conv7_w   = (const float*)d_in[9];
  const float* conv7_b   = (const float*)d_in[10];
  const float* gproj_w   = (const float*)d_in[11];
  const float* gproj_b   = (const float*)d_in[12];
  const float* lproj_w   = (const float*)d_in[13];
  const float* lproj_b   = (const float*)d_in[14];
  const float* fus_w     = (const float*)d_in[15];
  const float* fus_b     = (const float*)d_in[16];
  const float* glce_g    = (const float*)d_in[17];
  const float* glce_bb   = (const float*)d_in[18];
  const float* ssm_g     = (const float*)d_in[19];
  const float* ssm_bb    = (const float*)d_in[20];
  const float* in_w[2]   = {(const float*)d_in[21], (const float*)d_in[30]};
  const float* cw[2]     = {(const float*)d_in[22], (const float*)d_in[31]};
  const float* cb[2]     = {(const float*)d_in[23], (const float*)d_in[32]};
  const float* xp_w[2]   = {(const float*)d_in[24], (const float*)d_in[33]};
  const float* dt_w[2]   = {(const float*)d_in[25], (const float*)d_in[34]};
  const float* dt_b[2]   = {(const float*)d_in[26], (const float*)d_in[35]};
  const float* A_log[2]  = {(const float*)d_in[27], (const float*)d_in[36]};
  const float* Dp[2]     = {(const float*)d_in[28], (const float*)d_in[37]};
  const float* out_w[2]  = {(const float*)d_in[29], (const float*)d_in[38]};
  const float* ffn_g     = (const float*)d_in[39];
  const float* ffn_bb    = (const float*)d_in[40];
  const float* gate_w    = (const float*)d_in[41];
  const float* up_w      = (const float*)d_in[42];
  const float* down_w    = (const float*)d_in[43];

  float* ws = (float*)d_ws;
  size_t off = 0;
  const size_t M = 2048;
  auto take = [&](size_t n) { float* p = ws + off; off += n; return p; };
  float* QKV   = take(M * 2304);
  float* AO    = take(M * 768);
  float* AO2   = take(M * 768);
  float* GL    = take(M * 768);
  float* LOC   = take(M * 768);
  float* T1    = take(M * 768);
  float* X1    = take(M * 768);
  float* XN    = take(M * 768);
  float* XIZ   = take(M * 3072);
  float* XC    = take(M * 1536);
  float* DBC   = take(M * 80);
  float* DELTA = take(M * 1536);
  float* YG    = take(M * 1536);
  float* YF    = take(M * 768);
  float* YB    = take(M * 768);
  float* X2    = take(M * 768);
  float* GU    = XIZ;  // reuse (mamba finished before FFN)
  float* YFB[2] = {YF, YB};

  dim3 blk(256);

  // --- GLCE branch ---
  gemm_f32<<<dim3(36, 32), blk, 0, stream>>>(x, 768, 0, qkv_w, qkv_b, nullptr,
                                             QKV, 2304, 0, 0, 2304, 768, 0, 0);
  attn_f32<<<dim3(LSEQ / TQ, 16), blk, 0, stream>>>(QKV, AO);
  gemm_f32<<<dim3(12, 32), blk, 0, stream>>>(AO, 768, 0, att_out_w, att_out_b, nullptr,
                                             AO2, 768, 0, 0, 768, 768, 0, 0);
  gemm_f32<<<dim3(6, 32), blk, 0, stream>>>(AO2, 768, 0, gproj_w, gproj_b, nullptr,
                                            GL, 768, 0, 0, 384, 768, 0, 0);
  glce_conv<<<dim3(M * 768 / 256), blk, 0, stream>>>(x, conv3_w, conv3_b, conv5_w,
                                                     conv5_b, conv7_w, conv7_b, LOC);
  gemm_f32<<<dim3(6, 32), blk, 0, stream>>>(LOC, 768, 0, lproj_w, lproj_b, nullptr,
                                            GL, 768, 384, 0, 384, 768, 0, 0);
  gemm_f32<<<dim3(12, 32), blk, 0, stream>>>(GL, 768, 0, fus_w, fus_b, x,
                                             T1, 768, 0, 0, 768, 768, 0, 0);
  ln_f32<<<dim3(512), blk, 0, stream>>>(T1, glce_g, glce_bb, X1);

  // --- bidirectional mamba ---
  ln_f32<<<dim3(512), blk, 0, stream>>>(X1, ssm_g, ssm_bb, XN);
  for (int dir = 0; dir < 2; ++dir) {
    int flip = dir;
    gemm_f32<<<dim3(48, 32), blk, 0, stream>>>(XN, 768, flip, in_w[dir], nullptr, nullptr,
                                               XIZ, 3072, 0, 0, 3072, 768, 0, 0);
    mamba_conv_f32<<<dim3(M * 1536 / 256), blk, 0, stream>>>(XIZ, cw[dir], cb[dir], XC);
    gemm_f32<<<dim3(2, 32), blk, 0, stream>>>(XC, 1536, 0, xp_w[dir], nullptr, nullptr,
                                              DBC, 80, 0, 0, 80, 1536, 0, 0);
    gemm_f32<<<dim3(24, 32), blk, 0, stream>>>(DBC, 80, 0, dt_w[dir], dt_b[dir], nullptr,
                                               DELTA, 1536, 0, 0, 1536, 48, 1, 0);
    mamba_scan_f32<<<dim3(12), blk, 0, stream>>>(DBC, DELTA, XC, XIZ, A_log[dir],
                                                 Dp[dir], YG);
    gemm_f32<<<dim3(12, 32), blk, 0, stream>>>(YG, 1536, 0, out_w[dir], nullptr, nullptr,
                                               YFB[dir], 768, 0, flip, 768, 1536, 0, 0);
  }
  add3_f32<<<dim3(M * 768 / 256), blk, 0, stream>>>(X1, YF, YB, X2);

  // --- FFN ---
  ln_f32<<<dim3(512), blk, 0, stream>>>(X2, ffn_g, ffn_bb, XN);
  gemm_f32<<<dim3(48, 32), blk, 0, stream>>>(XN, 768, 0, gate_w, nullptr, nullptr,
                                             GU, 3072, 0, 0, 3072, 768, 2, 0);
  gemm_f32<<<dim3(48, 32), blk, 0, stream>>>(XN, 768, 0, up_w, nullptr, nullptr,
                                             GU, 3072, 0, 0, 3072, 768, 0, 1);
  gemm_f32<<<dim3(12, 32), blk, 0, stream>>>(GU, 3072, 0, down_w, nullptr, X2,
                                             (float*)d_out, 768, 0, 0, 768, 3072, 0, 0);
}

// Round 2
// 2022.671 us; speedup vs baseline: 2.7443x; 2.7443x over previous
//
#include <hip/hip_runtime.h>
#include <math.h>

#define LSEQ 1024
#define DMODEL 768
#define NHEAD 8
#define HDIM 96
#define DI_ 1536
#define NST 16
#define DTR_ 48
#define FF_ 3072

typedef __attribute__((ext_vector_type(8))) short short8;
typedef __attribute__((ext_vector_type(4))) short short4_t;
typedef __attribute__((ext_vector_type(4))) float f32x4;

__device__ inline short f2bf(float f) {
  unsigned u = __builtin_bit_cast(unsigned, f);
  unsigned r = u + 0x7FFFu + ((u >> 16) & 1u);   // round-to-nearest-even
  return (short)(r >> 16);
}

// ---------------------------------------------------------------------------
// bf16 MFMA GEMM: C[m,n] = act( A[m,:] . W[n,:] + bias[n] ) (+residual / *=C)
// A (2048 x lda) fp32 row-major (rows b*L+l, optional l-flip), W (Ncols x Kd)
// fp32 row-major. Inputs converted to bf16 during LDS staging.
// Tile 64x64, BK=32, 4 waves; wave w does rows [w*16,w*16+16) x 64 cols.
// ---------------------------------------------------------------------------
__global__ __launch_bounds__(256) void gemm_bf16(
    const float* __restrict__ A, int lda, int flipA,
    const float* __restrict__ W,
    const float* __restrict__ bias,
    const float* __restrict__ residual,
    float* __restrict__ C, int ldc, int colOff, int flipC,
    int Ncols, int Kd, int act, int mulC)
{
  __shared__ short As[64][40];
  __shared__ short Ws[64][40];
  const int row0 = blockIdx.y * 64, col0 = blockIdx.x * 64;
  const int tid = threadIdx.x;
  const int w = tid >> 6, lane = tid & 63;
  const int m16 = lane & 15, kg = lane >> 4;

  f32x4 acc[4];
  #pragma unroll
  for (int i = 0; i < 4; ++i) acc[i] = (f32x4)(0.f);

  // staging pointers: thread covers rows {tid>>3, +32}, k-offset (tid&7)*4
  const int r8 = tid >> 3;
  const int kk = (tid & 7) << 2;
  const float* aptr[2];
  const float* wptr[2];
  int srow[2];
  #pragma unroll
  for (int u = 0; u < 2; ++u) {
    int gm = row0 + (u << 5) + r8;
    int bb = gm >> 10, ll = gm & 1023;
    if (flipA) ll = 1023 - ll;
    aptr[u] = A + (size_t)(bb * LSEQ + ll) * lda + kk;
    int gn = col0 + (u << 5) + r8;
    if (gn >= Ncols) gn = Ncols - 1;      // clamp: values discarded in epilogue
    wptr[u] = W + (size_t)gn * Kd + kk;
    srow[u] = (u << 5) + r8;
  }

  for (int k0 = 0; k0 < Kd; k0 += 32) {
    #pragma unroll
    for (int u = 0; u < 2; ++u) {
      const int gk = k0 + kk;
      float4 av, wv;
      if (gk + 3 < Kd) {
        av = *(const float4*)(aptr[u] + k0);
        wv = *(const float4*)(wptr[u] + k0);
      } else {
        float ae[4], we[4];
        #pragma unroll
        for (int e = 0; e < 4; ++e) {
          bool in = (gk + e < Kd);
          ae[e] = in ? aptr[u][k0 + e] : 0.f;
          we[e] = in ? wptr[u][k0 + e] : 0.f;
        }
        av = make_float4(ae[0], ae[1], ae[2], ae[3]);
        wv = make_float4(we[0], we[1], we[2], we[3]);
      }
      short4_t ap = {f2bf(av.x), f2bf(av.y), f2bf(av.z), f2bf(av.w)};
      short4_t wp = {f2bf(wv.x), f2bf(wv.y), f2bf(wv.z), f2bf(wv.w)};
      *(short4_t*)&As[srow[u]][kk] = ap;
      *(short4_t*)&Ws[srow[u]][kk] = wp;
    }
    __syncthreads();
    short8 a = *(const short8*)&As[(w << 4) + m16][kg << 3];
    #pragma unroll
    for (int nt = 0; nt < 4; ++nt) {
      short8 b = *(const short8*)&Ws[(nt << 4) + m16][kg << 3];
      acc[nt] = __builtin_amdgcn_mfma_f32_16x16x32_bf16(a, b, acc[nt], 0, 0, 0);
    }
    __syncthreads();
  }

  #pragma unroll
  for (int nt = 0; nt < 4; ++nt) {
    int gn = col0 + (nt << 4) + m16;
    if (gn >= Ncols) continue;
    float bv = bias ? bias[gn] : 0.f;
    #pragma unroll
    for (int r = 0; r < 4; ++r) {
      int gm = row0 + (w << 4) + (kg << 2) + r;
      int bb = gm >> 10, ll = gm & 1023;
      if (flipC) ll = 1023 - ll;
      float v = acc[nt][r] + bv;
      if (act == 1) v = fmaxf(v, 0.f) + log1pf(__expf(-fabsf(v)));   // softplus
      else if (act == 2) v = v / (1.f + __expf(-v));                 // silu
      size_t idx = (size_t)(bb * LSEQ + ll) * ldc + colOff + gn;
      if (mulC) C[idx] *= v;
      else if (residual) C[idx] = residual[idx] + v;
      else C[idx] = v;
    }
  }
}

// ---------------------------------------------------------------------------
// fp32 GEMM (kept for the small, numerically sensitive xp/dt projections)
// ---------------------------------------------------------------------------
__global__ __launch_bounds__(256) void gemm_f32(
    const float* __restrict__ A, int lda, int flipA,
    const float* __restrict__ W,
    const float* __restrict__ bias,
    const float* __restrict__ residual,
    float* __restrict__ C, int ldc, int colOff, int flipC,
    int Ncols, int Kd, int act, int mulC)
{
  __shared__ float As[16][65];
  __shared__ float Bs[16][65];
  const int row0 = blockIdx.y * 64, col0 = blockIdx.x * 64;
  const int tid = threadIdx.x;
  const int tx = tid & 15, ty = tid >> 4;
  float acc[4][4] = {};
  const int lm = tid >> 2;
  const int lk = (tid & 3) << 2;
  int gmL = row0 + lm;
  int bbL = gmL >> 10, llL = gmL & 1023;
  if (flipA) llL = LSEQ - 1 - llL;
  const float* arow = A + (size_t)(bbL * LSEQ + llL) * lda;
  int gnL = col0 + lm;
  const bool wvalid = (gnL < Ncols);
  const float* wrow = W + (size_t)(wvalid ? gnL : 0) * Kd;

  for (int k0 = 0; k0 < Kd; k0 += 16) {
    #pragma unroll
    for (int u = 0; u < 4; ++u) {
      int kkk = k0 + lk + u;
      bool kin = (kkk < Kd);
      As[lk + u][lm] = kin ? arow[kkk] : 0.f;
      Bs[lk + u][lm] = (kin && wvalid) ? wrow[kkk] : 0.f;
    }
    __syncthreads();
    #pragma unroll
    for (int kkk = 0; kkk < 16; ++kkk) {
      float a[4], bv[4];
      #pragma unroll
      for (int i = 0; i < 4; ++i) a[i] = As[kkk][(ty << 2) + i];
      #pragma unroll
      for (int j = 0; j < 4; ++j) bv[j] = Bs[kkk][(tx << 2) + j];
      #pragma unroll
      for (int i = 0; i < 4; ++i)
        #pragma unroll
        for (int j = 0; j < 4; ++j)
          acc[i][j] = fmaf(a[i], bv[j], acc[i][j]);
    }
    __syncthreads();
  }

  #pragma unroll
  for (int i = 0; i < 4; ++i) {
    int gm = row0 + (ty << 2) + i;
    int bb = gm >> 10, ll = gm & 1023;
    if (flipC) ll = LSEQ - 1 - ll;
    size_t base = (size_t)(bb * LSEQ + ll) * ldc + colOff;
    #pragma unroll
    for (int j = 0; j < 4; ++j) {
      int gn = col0 + (tx << 2) + j;
      if (gn >= Ncols) continue;
      float v = acc[i][j];
      if (bias) v += bias[gn];
      if (act == 1) v = fmaxf(v, 0.f) + log1pf(__expf(-fabsf(v)));
      else if (act == 2) v = v / (1.f + __expf(-v));
      size_t idx = base + gn;
      if (mulC) C[idx] *= v;
      else if (residual) C[idx] = residual[idx] + v;
      else C[idx] = v;
    }
  }
}

// ---------------------------------------------------------------------------
// Attention (fp32, scores in LDS). One block = one (b,h) x 8 query rows.
// ---------------------------------------------------------------------------
#define TQ 8
__global__ __launch_bounds__(256) void attn_f32(const float* __restrict__ qkv,
                                                float* __restrict__ o)
{
  __shared__ float S[TQ][LSEQ + 1];
  __shared__ float Q[TQ][HDIM + 4];
  __shared__ float red[TQ][32];
  __shared__ float rowstat[TQ];
  const int bh = blockIdx.y;
  const int b_ = bh >> 3, h = bh & 7;
  const int q0 = blockIdx.x * TQ;
  const int tid = threadIdx.x;

  for (int i = tid; i < TQ * HDIM; i += 256) {
    int r = i / HDIM, dd = i - r * HDIM;
    Q[r][dd] = qkv[((size_t)(b_ * LSEQ) + q0 + r) * 2304 + h * HDIM + dd];
  }
  __syncthreads();

  const int r = tid & 7, jc = tid >> 3;
  const float scale = 0.1020620726159658f; // 1/sqrt(96)

  for (int t = 0; t < LSEQ / 32; ++t) {
    int j = jc + 32 * t;
    const float* kp = qkv + ((size_t)(b_ * LSEQ) + j) * 2304 + DMODEL + h * HDIM;
    float s = 0.f;
    #pragma unroll 8
    for (int dd = 0; dd < HDIM; ++dd) s = fmaf(Q[r][dd], kp[dd], s);
    S[r][j] = s * scale;
  }
  __syncthreads();

  float pm = -1e30f;
  for (int t = 0; t < 32; ++t) pm = fmaxf(pm, S[r][jc + 32 * t]);
  red[r][jc] = pm;
  __syncthreads();
  if (tid < TQ) {
    float m = -1e30f;
    for (int u = 0; u < 32; ++u) m = fmaxf(m, red[tid][u]);
    rowstat[tid] = m;
  }
  __syncthreads();
  float m = rowstat[r];
  float ps = 0.f;
  for (int t = 0; t < 32; ++t) {
    int j = jc + 32 * t;
    float e = __expf(S[r][j] - m);
    S[r][j] = e;
    ps += e;
  }
  red[r][jc] = ps;
  __syncthreads();
  if (tid < TQ) {
    float ssum = 0.f;
    for (int u = 0; u < 32; ++u) ssum += red[tid][u];
    rowstat[tid] = ssum;
  }
  __syncthreads();
  const float inv = 1.f / rowstat[r];

  float acc0 = 0.f, acc1 = 0.f, acc2 = 0.f;
  for (int j = 0; j < LSEQ; ++j) {
    float p = S[r][j];
    const float* vp = qkv + ((size_t)(b_ * LSEQ) + j) * 2304 + 2 * DMODEL + h * HDIM + jc;
    acc0 = fmaf(p, vp[0], acc0);
    acc1 = fmaf(p, vp[32], acc1);
    acc2 = fmaf(p, vp[64], acc2);
  }
  float* op = o + ((size_t)(b_ * LSEQ) + q0 + r) * DMODEL + h * HDIM + jc;
  op[0]  = acc0 * inv;
  op[32] = acc1 * inv;
  op[64] = acc2 * inv;
}

// ---------------------------------------------------------------------------
// GLCE convs (kernels 3/5/7, 3 in-ch per out-ch, exact gelu)
// ---------------------------------------------------------------------------
__global__ __launch_bounds__(256) void glce_conv(
    const float* __restrict__ x,
    const float* __restrict__ w3, const float* __restrict__ b3,
    const float* __restrict__ w5, const float* __restrict__ b5,
    const float* __restrict__ w7, const float* __restrict__ b7,
    float* __restrict__ loc)
{
  int idx = blockIdx.x * 256 + threadIdx.x;
  int c = idx % DMODEL;
  int bl = idx / DMODEL;
  int l = bl & 1023, b_ = bl >> 10;
  int cs = c >> 8, ch = c & 255;
  const float* wp; float bias; int kt, pad;
  if (cs == 0)      { wp = w3 + ch * 9;  bias = b3[ch]; kt = 3; pad = 1; }
  else if (cs == 1) { wp = w5 + ch * 15; bias = b5[ch]; kt = 5; pad = 2; }
  else              { wp = w7 + ch * 21; bias = b7[ch]; kt = 7; pad = 3; }
  float acc = bias;
  const float* xb = x + (size_t)(b_ * LSEQ) * DMODEL;
  for (int i = 0; i < 3; ++i) {
    int d = 3 * ch + i;
    for (int t = 0; t < kt; ++t) {
      int ls = l - pad + t;
      if (ls >= 0 && ls < LSEQ)
        acc = fmaf(xb[(size_t)ls * DMODEL + d], wp[i * kt + t], acc);
    }
  }
  loc[idx] = 0.5f * acc * (1.f + erff(acc * 0.7071067811865475f));
}

// ---------------------------------------------------------------------------
// Mamba depthwise causal conv (K=4) + silu
// ---------------------------------------------------------------------------
__global__ __launch_bounds__(256) void mamba_conv_f32(
    const float* __restrict__ xiz, const float* __restrict__ cw,
    const float* __restrict__ cb, float* __restrict__ xc)
{
  int idx = blockIdx.x * 256 + threadIdx.x;
  int d = idx % DI_;
  int bl = idx / DI_;
  int l = bl & 1023, b_ = bl >> 10;
  const float* w = cw + d * 4;
  float acc = cb[d];
  #pragma unroll
  for (int t = 0; t < 4; ++t) {
    int ls = l - 3 + t;
    if (ls >= 0)
      acc = fmaf(xiz[((size_t)(b_ * LSEQ + ls)) * 3072 + d], w[t], acc);
  }
  xc[idx] = acc / (1.f + __expf(-acc));
}

// ---------------------------------------------------------------------------
// Selective scan, one thread per (b,d,n). 192 blocks x 256 threads.
// Block: 16 d's x 16 n's. Sum over n via shfl_xor within 16-lane groups.
// ---------------------------------------------------------------------------
__global__ __launch_bounds__(256) void mamba_scan_f32(
    const float* __restrict__ dbc, const float* __restrict__ delta,
    const float* __restrict__ xc, const float* __restrict__ xiz,
    const float* __restrict__ A_log, const float* __restrict__ Dp,
    float* __restrict__ yg)
{
  const int b_ = blockIdx.x / 96;
  const int d0 = (blockIdx.x % 96) * 16;
  const int tid = threadIdx.x;
  const int dl = tid >> 4;     // local d (0..15)
  const int n  = tid & 15;
  const int d  = d0 + dl;
  const float a2 = -__expf(A_log[d * 16 + n]) * 1.4426950408889634f; // A*log2e
  const float dv = Dp[d];
  float h = 0.f;

  __shared__ float sdel[64][16];
  __shared__ float sxc[64][16];
  __shared__ float sz[64][16];
  __shared__ float sB[64][16];
  __shared__ float sC[64][16];
  __shared__ float sy[64][16];
  const size_t rowb = (size_t)b_ * LSEQ;

  for (int l0 = 0; l0 < LSEQ; l0 += 64) {
    __syncthreads();
    #pragma unroll
    for (int k = 0; k < 4; ++k) {
      int i = tid + k * 256;            // 0..1023
      int lc = i >> 4, c = i & 15;
      size_t row = rowb + l0 + lc;
      sdel[lc][c] = delta[row * 1536 + d0 + c];
      sxc[lc][c]  = xc[row * 1536 + d0 + c];
      sz[lc][c]   = xiz[row * 3072 + 1536 + d0 + c];
      sB[lc][c]   = dbc[row * 80 + 48 + c];
      sC[lc][c]   = dbc[row * 80 + 64 + c];
    }
    __syncthreads();
    for (int lc = 0; lc < 64; ++lc) {
      float dlv = sdel[lc][dl];
      float xv  = sxc[lc][dl];
      float dA = exp2f(dlv * a2);
      h = fmaf(dA, h, dlv * xv * sB[lc][n]);
      float p = h * sC[lc][n];
      p += __shfl_xor(p, 1);
      p += __shfl_xor(p, 2);
      p += __shfl_xor(p, 4);
      p += __shfl_xor(p, 8);
      if (n == 0) {
        float zv = sz[lc][dl];
        float y = p + xv * dv;
        sy[lc][dl] = y * (zv / (1.f + __expf(-zv)));
      }
    }
    __syncthreads();
    #pragma unroll
    for (int k = 0; k < 4; ++k) {
      int i = tid + k * 256;
      int lc = i >> 4, c = i & 15;
      yg[(rowb + l0 + lc) * 1536 + d0 + c] = sy[lc][c];
    }
  }
}

// ---------------------------------------------------------------------------
// LayerNorm over last dim (768)
// ---------------------------------------------------------------------------
__global__ __launch_bounds__(256) void ln_f32(
    const float* __restrict__ in, const float* __restrict__ g,
    const float* __restrict__ b, float* __restrict__ out)
{
  int row = blockIdx.x * 4 + (threadIdx.x >> 6);
  int lane = threadIdx.x & 63;
  const float* xr = in + (size_t)row * DMODEL;
  float v[12];
  float s = 0.f, s2 = 0.f;
  #pragma unroll
  for (int i = 0; i < 12; ++i) {
    float t = xr[i * 64 + lane];
    v[i] = t; s += t; s2 = fmaf(t, t, s2);
  }
  #pragma unroll
  for (int off = 1; off < 64; off <<= 1) {
    s += __shfl_xor(s, off);
    s2 += __shfl_xor(s2, off);
  }
  float mean = s * (1.f / 768.f);
  float var = s2 * (1.f / 768.f) - mean * mean;
  float inv = rsqrtf(var + 1e-5f);
  float* orow = out + (size_t)row * DMODEL;
  #pragma unroll
  for (int i = 0; i < 12; ++i) {
    int c = i * 64 + lane;
    orow[c] = (v[i] - mean) * inv * g[c] + b[c];
  }
}

__global__ __launch_bounds__(256) void add3_f32(
    const float* __restrict__ a, const float* __restrict__ b,
    const float* __restrict__ c, float* __restrict__ o)
{
  int i = blockIdx.x * 256 + threadIdx.x;
  o[i] = a[i] + b[i] + c[i];
}

// ---------------------------------------------------------------------------
extern "C" void kernel_launch(void* const* d_in, const int* in_sizes, int n_in,
                              void* d_out, int out_size, void* d_ws, size_t ws_size,
                              hipStream_t stream)
{
  (void)in_sizes; (void)n_in; (void)out_size; (void)ws_size;
  const float* x         = (const float*)d_in[0];
  const float* qkv_w     = (const float*)d_in[1];
  const float* qkv_b     = (const float*)d_in[2];
  const float* att_out_w = (const float*)d_in[3];
  const float* att_out_b = (const float*)d_in[4];
  const float* conv3_w   = (const float*)d_in[5];
  const float* conv3_b   = (const float*)d_in[6];
  const float* conv5_w   = (const float*)d_in[7];
  const float* conv5_b   = (const float*)d_in[8];
  const float* conv7_w   = (const float*)d_in[9];
  const float* conv7_b   = (const float*)d_in[10];
  const float* gproj_w   = (const float*)d_in[11];
  const float* gproj_b   = (const float*)d_in[12];
  const float* lproj_w   = (const float*)d_in[13];
  const float* lproj_b   = (const float*)d_in[14];
  const float* fus_w     = (const float*)d_in[15];
  const float* fus_b     = (const float*)d_in[16];
  const float* glce_g    = (const float*)d_in[17];
  const float* glce_bb   = (const float*)d_in[18];
  const float* ssm_g     = (const float*)d_in[19];
  const float* ssm_bb    = (const float*)d_in[20];
  const float* in_w[2]   = {(const float*)d_in[21], (const float*)d_in[30]};
  const float* cw[2]     = {(const float*)d_in[22], (const float*)d_in[31]};
  const float* cb[2]     = {(const float*)d_in[23], (const float*)d_in[32]};
  const float* xp_w[2]   = {(const float*)d_in[24], (const float*)d_in[33]};
  const float* dt_w[2]   = {(const float*)d_in[25], (const float*)d_in[34]};
  const float* dt_b[2]   = {(const float*)d_in[26], (const float*)d_in[35]};
  const float* A_log[2]  = {(const float*)d_in[27], (const float*)d_in[36]};
  const float* Dp[2]     = {(const float*)d_in[28], (const float*)d_in[37]};
  const float* out_w[2]  = {(const float*)d_in[29], (const float*)d_in[38]};
  const float* ffn_g     = (const float*)d_in[39];
  const float* ffn_bb    = (const float*)d_in[40];
  const float* gate_w    = (const float*)d_in[41];
  const float* up_w      = (const float*)d_in[42];
  const float* down_w    = (const float*)d_in[43];

  float* ws = (float*)d_ws;
  size_t off = 0;
  const size_t M = 2048;
  auto take = [&](size_t n) { float* p = ws + off; off += n; return p; };
  float* QKV   = take(M * 2304);
  float* AO    = take(M * 768);
  float* AO2   = take(M * 768);
  float* GL    = take(M * 768);
  float* LOC   = take(M * 768);
  float* T1    = take(M * 768);
  float* X1    = take(M * 768);
  float* XN    = take(M * 768);
  float* XIZ   = take(M * 3072);
  float* XC    = take(M * 1536);
  float* DBC   = take(M * 80);
  float* DELTA = take(M * 1536);
  float* YG    = take(M * 1536);
  float* YF    = take(M * 768);
  float* YB    = take(M * 768);
  float* X2    = take(M * 768);
  float* GU    = XIZ;  // reuse (mamba finished before FFN)
  float* YFB[2] = {YF, YB};

  dim3 blk(256);

  // --- GLCE branch ---
  gemm_bf16<<<dim3(36, 32), blk, 0, stream>>>(x, 768, 0, qkv_w, qkv_b, nullptr,
                                              QKV, 2304, 0, 0, 2304, 768, 0, 0);
  attn_f32<<<dim3(LSEQ / TQ, 16), blk, 0, stream>>>(QKV, AO);
  gemm_bf16<<<dim3(12, 32), blk, 0, stream>>>(AO, 768, 0, att_out_w, att_out_b, nullptr,
                                              AO2, 768, 0, 0, 768, 768, 0, 0);
  gemm_bf16<<<dim3(6, 32), blk, 0, stream>>>(AO2, 768, 0, gproj_w, gproj_b, nullptr,
                                             GL, 768, 0, 0, 384, 768, 0, 0);
  glce_conv<<<dim3(M * 768 / 256), blk, 0, stream>>>(x, conv3_w, conv3_b, conv5_w,
                                                     conv5_b, conv7_w, conv7_b, LOC);
  gemm_bf16<<<dim3(6, 32), blk, 0, stream>>>(LOC, 768, 0, lproj_w, lproj_b, nullptr,
                                             GL, 768, 384, 0, 384, 768, 0, 0);
  gemm_bf16<<<dim3(12, 32), blk, 0, stream>>>(GL, 768, 0, fus_w, fus_b, x,
                                              T1, 768, 0, 0, 768, 768, 0, 0);
  ln_f32<<<dim3(512), blk, 0, stream>>>(T1, glce_g, glce_bb, X1);

  // --- bidirectional mamba ---
  ln_f32<<<dim3(512), blk, 0, stream>>>(X1, ssm_g, ssm_bb, XN);
  for (int dir = 0; dir < 2; ++dir) {
    int flip = dir;
    gemm_bf16<<<dim3(48, 32), blk, 0, stream>>>(XN, 768, flip, in_w[dir], nullptr, nullptr,
                                                XIZ, 3072, 0, 0, 3072, 768, 0, 0);
    mamba_conv_f32<<<dim3(M * 1536 / 256), blk, 0, stream>>>(XIZ, cw[dir], cb[dir], XC);
    gemm_f32<<<dim3(2, 32), blk, 0, stream>>>(XC, 1536, 0, xp_w[dir], nullptr, nullptr,
                                              DBC, 80, 0, 0, 80, 1536, 0, 0);
    gemm_f32<<<dim3(24, 32), blk, 0, stream>>>(DBC, 80, 0, dt_w[dir], dt_b[dir], nullptr,
                                               DELTA, 1536, 0, 0, 1536, 48, 1, 0);
    mamba_scan_f32<<<dim3(192), blk, 0, stream>>>(DBC, DELTA, XC, XIZ, A_log[dir],
                                                  Dp[dir], YG);
    gemm_bf16<<<dim3(12, 32), blk, 0, stream>>>(YG, 1536, 0, out_w[dir], nullptr, nullptr,
                                                YFB[dir], 768, 0, flip, 768, 1536, 0, 0);
  }
  add3_f32<<<dim3(M * 768 / 256), blk, 0, stream>>>(X1, YF, YB, X2);

  // --- FFN ---
  ln_f32<<<dim3(512), blk, 0, stream>>>(X2, ffn_g, ffn_bb, XN);
  gemm_bf16<<<dim3(48, 32), blk, 0, stream>>>(XN, 768, 0, gate_w, nullptr, nullptr,
                                              GU, 3072, 0, 0, 3072, 768, 2, 0);
  gemm_bf16<<<dim3(48, 32), blk, 0, stream>>>(XN, 768, 0, up_w, nullptr, nullptr,
                                              GU, 3072, 0, 0, 3072, 768, 0, 1);
  gemm_bf16<<<dim3(12, 32), blk, 0, stream>>>(GU, 3072, 0, down_w, nullptr, X2,
                                              (float*)d_out, 768, 0, 0, 768, 3072, 0, 0);
}

// Round 3
// 1673.021 us; speedup vs baseline: 3.3178x; 1.2090x over previous
//
#include <hip/hip_runtime.h>
#include <math.h>

#define LSEQ 1024
#define DMODEL 768
#define NHEAD 8
#define HDIM 96
#define DI_ 1536
#define NST 16
#define DTR_ 48
#define FF_ 3072

typedef __attribute__((ext_vector_type(8))) short short8;
typedef __attribute__((ext_vector_type(4))) short short4_t;
typedef __attribute__((ext_vector_type(4))) float f32x4;

__device__ inline short f2bf(float f) {
  unsigned u = __builtin_bit_cast(unsigned, f);
  unsigned r = u + 0x7FFFu + ((u >> 16) & 1u);   // round-to-nearest-even
  return (short)(r >> 16);
}

// ---------------------------------------------------------------------------
// bf16 MFMA GEMM: C[m,n] = act( A[m,:] . W[n,:] + bias[n] ) (+residual / *=C)
// ---------------------------------------------------------------------------
__global__ __launch_bounds__(256) void gemm_bf16(
    const float* __restrict__ A, int lda, int flipA,
    const float* __restrict__ W,
    const float* __restrict__ bias,
    const float* __restrict__ residual,
    float* __restrict__ C, int ldc, int colOff, int flipC,
    int Ncols, int Kd, int act, int mulC)
{
  __shared__ short As[64][40];
  __shared__ short Ws[64][40];
  const int row0 = blockIdx.y * 64, col0 = blockIdx.x * 64;
  const int tid = threadIdx.x;
  const int w = tid >> 6, lane = tid & 63;
  const int m16 = lane & 15, kg = lane >> 4;

  f32x4 acc[4];
  #pragma unroll
  for (int i = 0; i < 4; ++i) acc[i] = (f32x4)(0.f);

  const int r8 = tid >> 3;
  const int kk = (tid & 7) << 2;
  const float* aptr[2];
  const float* wptr[2];
  int srow[2];
  #pragma unroll
  for (int u = 0; u < 2; ++u) {
    int gm = row0 + (u << 5) + r8;
    int bb = gm >> 10, ll = gm & 1023;
    if (flipA) ll = 1023 - ll;
    aptr[u] = A + (size_t)(bb * LSEQ + ll) * lda + kk;
    int gn = col0 + (u << 5) + r8;
    if (gn >= Ncols) gn = Ncols - 1;
    wptr[u] = W + (size_t)gn * Kd + kk;
    srow[u] = (u << 5) + r8;
  }

  for (int k0 = 0; k0 < Kd; k0 += 32) {
    #pragma unroll
    for (int u = 0; u < 2; ++u) {
      const int gk = k0 + kk;
      float4 av, wv;
      if (gk + 3 < Kd) {
        av = *(const float4*)(aptr[u] + k0);
        wv = *(const float4*)(wptr[u] + k0);
      } else {
        float ae[4], we[4];
        #pragma unroll
        for (int e = 0; e < 4; ++e) {
          bool in = (gk + e < Kd);
          ae[e] = in ? aptr[u][k0 + e] : 0.f;
          we[e] = in ? wptr[u][k0 + e] : 0.f;
        }
        av = make_float4(ae[0], ae[1], ae[2], ae[3]);
        wv = make_float4(we[0], we[1], we[2], we[3]);
      }
      short4_t ap = {f2bf(av.x), f2bf(av.y), f2bf(av.z), f2bf(av.w)};
      short4_t wp = {f2bf(wv.x), f2bf(wv.y), f2bf(wv.z), f2bf(wv.w)};
      *(short4_t*)&As[srow[u]][kk] = ap;
      *(short4_t*)&Ws[srow[u]][kk] = wp;
    }
    __syncthreads();
    short8 a = *(const short8*)&As[(w << 4) + m16][kg << 3];
    #pragma unroll
    for (int nt = 0; nt < 4; ++nt) {
      short8 b = *(const short8*)&Ws[(nt << 4) + m16][kg << 3];
      acc[nt] = __builtin_amdgcn_mfma_f32_16x16x32_bf16(a, b, acc[nt], 0, 0, 0);
    }
    __syncthreads();
  }

  #pragma unroll
  for (int nt = 0; nt < 4; ++nt) {
    int gn = col0 + (nt << 4) + m16;
    if (gn >= Ncols) continue;
    float bv = bias ? bias[gn] : 0.f;
    #pragma unroll
    for (int r = 0; r < 4; ++r) {
      int gm = row0 + (w << 4) + (kg << 2) + r;
      int bb = gm >> 10, ll = gm & 1023;
      if (flipC) ll = 1023 - ll;
      float v = acc[nt][r] + bv;
      if (act == 1) v = fmaxf(v, 0.f) + log1pf(__expf(-fabsf(v)));   // softplus
      else if (act == 2) v = v / (1.f + __expf(-v));                 // silu
      size_t idx = (size_t)(bb * LSEQ + ll) * ldc + colOff + gn;
      if (mulC) C[idx] *= v;
      else if (residual) C[idx] = residual[idx] + v;
      else C[idx] = v;
    }
  }
}

// ---------------------------------------------------------------------------
// fp32 GEMM (small, numerically sensitive xp/dt projections)
// ---------------------------------------------------------------------------
__global__ __launch_bounds__(256) void gemm_f32(
    const float* __restrict__ A, int lda, int flipA,
    const float* __restrict__ W,
    const float* __restrict__ bias,
    const float* __restrict__ residual,
    float* __restrict__ C, int ldc, int colOff, int flipC,
    int Ncols, int Kd, int act, int mulC)
{
  __shared__ float As[16][65];
  __shared__ float Bs[16][65];
  const int row0 = blockIdx.y * 64, col0 = blockIdx.x * 64;
  const int tid = threadIdx.x;
  const int tx = tid & 15, ty = tid >> 4;
  float acc[4][4] = {};
  const int lm = tid >> 2;
  const int lk = (tid & 3) << 2;
  int gmL = row0 + lm;
  int bbL = gmL >> 10, llL = gmL & 1023;
  if (flipA) llL = LSEQ - 1 - llL;
  const float* arow = A + (size_t)(bbL * LSEQ + llL) * lda;
  int gnL = col0 + lm;
  const bool wvalid = (gnL < Ncols);
  const float* wrow = W + (size_t)(wvalid ? gnL : 0) * Kd;

  for (int k0 = 0; k0 < Kd; k0 += 16) {
    #pragma unroll
    for (int u = 0; u < 4; ++u) {
      int kkk = k0 + lk + u;
      bool kin = (kkk < Kd);
      As[lk + u][lm] = kin ? arow[kkk] : 0.f;
      Bs[lk + u][lm] = (kin && wvalid) ? wrow[kkk] : 0.f;
    }
    __syncthreads();
    #pragma unroll
    for (int kkk = 0; kkk < 16; ++kkk) {
      float a[4], bv[4];
      #pragma unroll
      for (int i = 0; i < 4; ++i) a[i] = As[kkk][(ty << 2) + i];
      #pragma unroll
      for (int j = 0; j < 4; ++j) bv[j] = Bs[kkk][(tx << 2) + j];
      #pragma unroll
      for (int i = 0; i < 4; ++i)
        #pragma unroll
        for (int j = 0; j < 4; ++j)
          acc[i][j] = fmaf(a[i], bv[j], acc[i][j]);
    }
    __syncthreads();
  }

  #pragma unroll
  for (int i = 0; i < 4; ++i) {
    int gm = row0 + (ty << 2) + i;
    int bb = gm >> 10, ll = gm & 1023;
    if (flipC) ll = LSEQ - 1 - ll;
    size_t base = (size_t)(bb * LSEQ + ll) * ldc + colOff;
    #pragma unroll
    for (int j = 0; j < 4; ++j) {
      int gn = col0 + (tx << 2) + j;
      if (gn >= Ncols) continue;
      float v = acc[i][j];
      if (bias) v += bias[gn];
      if (act == 1) v = fmaxf(v, 0.f) + log1pf(__expf(-fabsf(v)));
      else if (act == 2) v = v / (1.f + __expf(-v));
      size_t idx = base + gn;
      if (mulC) C[idx] *= v;
      else if (residual) C[idx] = residual[idx] + v;
      else C[idx] = v;
    }
  }
}

// ---------------------------------------------------------------------------
// MFMA flash attention. One block = one (b,h) x 64 q rows; 4 waves x 16 rows.
// KV tiles of 64 keys staged in LDS (K row-major, V transposed).
// Online softmax in base-2 domain; P re-laid out via per-wave LDS tile.
// ---------------------------------------------------------------------------
__global__ __launch_bounds__(256) void attn_mfma(const float* __restrict__ qkv,
                                                 float* __restrict__ o)
{
  __shared__ short Ks[64][104];     // [key][d]   (208 B rows: 16B-aligned, 2-way banks)
  __shared__ short Vt[96][72];      // [d][key]   (144 B rows)
  __shared__ short Ps[4][16][72];   // per-wave P [q][key]

  const int bh = blockIdx.y;
  const int b_ = bh >> 3, h = bh & 7;
  const int q0 = blockIdx.x * 64;
  const int tid = threadIdx.x;
  const int w = tid >> 6, lane = tid & 63;
  const int m16 = lane & 15, g4 = lane >> 4;

  // scale folded into base-2 softmax: s2 = S * (1/sqrt(96) * log2(e))
  const float sc2 = 0.10206207261596577f * 1.4426950408889634f;

  // Q fragments for this wave's 16 rows (A-frag: row=m16, k=g4*8+j)
  short8 qf[3];
  {
    const float* qrow = qkv + ((size_t)(b_ * LSEQ) + q0 + w * 16 + m16) * 2304 + h * HDIM;
    #pragma unroll
    for (int c = 0; c < 3; ++c) {
      float4 v0 = *(const float4*)(qrow + c * 32 + g4 * 8);
      float4 v1 = *(const float4*)(qrow + c * 32 + g4 * 8 + 4);
      qf[c] = short8{f2bf(v0.x), f2bf(v0.y), f2bf(v0.z), f2bf(v0.w),
                     f2bf(v1.x), f2bf(v1.y), f2bf(v1.z), f2bf(v1.w)};
    }
  }

  float m_run[4], l_run[4];
  #pragma unroll
  for (int r = 0; r < 4; ++r) { m_run[r] = -INFINITY; l_run[r] = 0.f; }
  f32x4 oacc[6];
  #pragma unroll
  for (int ct = 0; ct < 6; ++ct) oacc[ct] = (f32x4)(0.f);

  const int kr = tid >> 2;             // staging: key row 0..63
  const int cc = (tid & 3) * 24;       // d-offset 0/24/48/72

  for (int t = 0; t < LSEQ / 64; ++t) {
    const int k0 = t * 64;
    __syncthreads();   // previous tile's LDS fully consumed
    {
      const float* kp = qkv + ((size_t)(b_ * LSEQ) + k0 + kr) * 2304 + DMODEL + h * HDIM + cc;
      const float* vp = kp + DMODEL;
      #pragma unroll
      for (int u = 0; u < 6; ++u) {
        float4 kv = *(const float4*)(kp + u * 4);
        *(short4_t*)&Ks[kr][cc + u * 4] =
            short4_t{f2bf(kv.x), f2bf(kv.y), f2bf(kv.z), f2bf(kv.w)};
        float4 vv = *(const float4*)(vp + u * 4);
        Vt[cc + u * 4 + 0][kr] = f2bf(vv.x);
        Vt[cc + u * 4 + 1][kr] = f2bf(vv.y);
        Vt[cc + u * 4 + 2][kr] = f2bf(vv.z);
        Vt[cc + u * 4 + 3][kr] = f2bf(vv.w);
      }
    }
    __syncthreads();

    // S = Q K^T  (D: row=q=g4*4+r, col=key=kt*16+m16)
    f32x4 sacc[4];
    #pragma unroll
    for (int kt = 0; kt < 4; ++kt) sacc[kt] = (f32x4)(0.f);
    #pragma unroll
    for (int c = 0; c < 3; ++c) {
      #pragma unroll
      for (int kt = 0; kt < 4; ++kt) {
        short8 bfrag = *(const short8*)&Ks[kt * 16 + m16][c * 32 + g4 * 8];
        sacc[kt] = __builtin_amdgcn_mfma_f32_16x16x32_bf16(qf[c], bfrag, sacc[kt], 0, 0, 0);
      }
    }

    // online softmax (base-2)
    #pragma unroll
    for (int r = 0; r < 4; ++r) {
      float s0 = sacc[0][r] * sc2, s1 = sacc[1][r] * sc2;
      float s2v = sacc[2][r] * sc2, s3 = sacc[3][r] * sc2;
      float mv = fmaxf(fmaxf(s0, s1), fmaxf(s2v, s3));
      mv = fmaxf(mv, __shfl_xor(mv, 1));
      mv = fmaxf(mv, __shfl_xor(mv, 2));
      mv = fmaxf(mv, __shfl_xor(mv, 4));
      mv = fmaxf(mv, __shfl_xor(mv, 8));
      float mnew = fmaxf(m_run[r], mv);
      float scale = exp2f(m_run[r] - mnew);
      float p0 = exp2f(s0 - mnew), p1 = exp2f(s1 - mnew);
      float p2 = exp2f(s2v - mnew), p3 = exp2f(s3 - mnew);
      short* pr = &Ps[w][g4 * 4 + r][m16];
      pr[0]  = f2bf(p0);
      pr[16] = f2bf(p1);
      pr[32] = f2bf(p2);
      pr[48] = f2bf(p3);
      float ps = p0 + p1 + p2 + p3;
      ps += __shfl_xor(ps, 1);
      ps += __shfl_xor(ps, 2);
      ps += __shfl_xor(ps, 4);
      ps += __shfl_xor(ps, 8);
      l_run[r] = l_run[r] * scale + ps;
      m_run[r] = mnew;
      #pragma unroll
      for (int ct = 0; ct < 6; ++ct) oacc[ct][r] *= scale;
    }

    // O += P V   (A-frag from Ps: row=q=m16, k=key; B-frag from Vt: col=d, k=key)
    #pragma unroll
    for (int kc = 0; kc < 2; ++kc) {
      short8 pa = *(const short8*)&Ps[w][m16][kc * 32 + g4 * 8];
      #pragma unroll
      for (int ct = 0; ct < 6; ++ct) {
        short8 vb = *(const short8*)&Vt[ct * 16 + m16][kc * 32 + g4 * 8];
        oacc[ct] = __builtin_amdgcn_mfma_f32_16x16x32_bf16(pa, vb, oacc[ct], 0, 0, 0);
      }
    }
  }

  // epilogue: normalize and store (row=q=g4*4+r, col=d=ct*16+m16)
  #pragma unroll
  for (int r = 0; r < 4; ++r) {
    float inv = 1.f / l_run[r];
    float* orow = o + ((size_t)(b_ * LSEQ) + q0 + w * 16 + g4 * 4 + r) * DMODEL + h * HDIM;
    #pragma unroll
    for (int ct = 0; ct < 6; ++ct)
      orow[ct * 16 + m16] = oacc[ct][r] * inv;
  }
}

// ---------------------------------------------------------------------------
// GLCE convs (kernels 3/5/7, 3 in-ch per out-ch, exact gelu)
// ---------------------------------------------------------------------------
__global__ __launch_bounds__(256) void glce_conv(
    const float* __restrict__ x,
    const float* __restrict__ w3, const float* __restrict__ b3,
    const float* __restrict__ w5, const float* __restrict__ b5,
    const float* __restrict__ w7, const float* __restrict__ b7,
    float* __restrict__ loc)
{
  int idx = blockIdx.x * 256 + threadIdx.x;
  int c = idx % DMODEL;
  int bl = idx / DMODEL;
  int l = bl & 1023, b_ = bl >> 10;
  int cs = c >> 8, ch = c & 255;
  const float* wp; float bias; int kt, pad;
  if (cs == 0)      { wp = w3 + ch * 9;  bias = b3[ch]; kt = 3; pad = 1; }
  else if (cs == 1) { wp = w5 + ch * 15; bias = b5[ch]; kt = 5; pad = 2; }
  else              { wp = w7 + ch * 21; bias = b7[ch]; kt = 7; pad = 3; }
  float acc = bias;
  const float* xb = x + (size_t)(b_ * LSEQ) * DMODEL;
  for (int i = 0; i < 3; ++i) {
    int d = 3 * ch + i;
    for (int t = 0; t < kt; ++t) {
      int ls = l - pad + t;
      if (ls >= 0 && ls < LSEQ)
        acc = fmaf(xb[(size_t)ls * DMODEL + d], wp[i * kt + t], acc);
    }
  }
  loc[idx] = 0.5f * acc * (1.f + erff(acc * 0.7071067811865475f));
}

// ---------------------------------------------------------------------------
// Mamba depthwise causal conv (K=4) + silu
// ---------------------------------------------------------------------------
__global__ __launch_bounds__(256) void mamba_conv_f32(
    const float* __restrict__ xiz, const float* __restrict__ cw,
    const float* __restrict__ cb, float* __restrict__ xc)
{
  int idx = blockIdx.x * 256 + threadIdx.x;
  int d = idx % DI_;
  int bl = idx / DI_;
  int l = bl & 1023, b_ = bl >> 10;
  const float* w = cw + d * 4;
  float acc = cb[d];
  #pragma unroll
  for (int t = 0; t < 4; ++t) {
    int ls = l - 3 + t;
    if (ls >= 0)
      acc = fmaf(xiz[((size_t)(b_ * LSEQ + ls)) * 3072 + d], w[t], acc);
  }
  xc[idx] = acc / (1.f + __expf(-acc));
}

// ---------------------------------------------------------------------------
// Selective scan, one thread per (b,d,n). 192 blocks x 256 threads.
// ---------------------------------------------------------------------------
__global__ __launch_bounds__(256) void mamba_scan_f32(
    const float* __restrict__ dbc, const float* __restrict__ delta,
    const float* __restrict__ xc, const float* __restrict__ xiz,
    const float* __restrict__ A_log, const float* __restrict__ Dp,
    float* __restrict__ yg)
{
  const int b_ = blockIdx.x / 96;
  const int d0 = (blockIdx.x % 96) * 16;
  const int tid = threadIdx.x;
  const int dl = tid >> 4;
  const int n  = tid & 15;
  const int d  = d0 + dl;
  const float a2 = -__expf(A_log[d * 16 + n]) * 1.4426950408889634f;
  const float dv = Dp[d];
  float h = 0.f;

  __shared__ float sdel[64][16];
  __shared__ float sxc[64][16];
  __shared__ float sz[64][16];
  __shared__ float sB[64][16];
  __shared__ float sC[64][16];
  __shared__ float sy[64][16];
  const size_t rowb = (size_t)b_ * LSEQ;

  for (int l0 = 0; l0 < LSEQ; l0 += 64) {
    __syncthreads();
    #pragma unroll
    for (int k = 0; k < 4; ++k) {
      int i = tid + k * 256;
      int lc = i >> 4, c = i & 15;
      size_t row = rowb + l0 + lc;
      sdel[lc][c] = delta[row * 1536 + d0 + c];
      sxc[lc][c]  = xc[row * 1536 + d0 + c];
      sz[lc][c]   = xiz[row * 3072 + 1536 + d0 + c];
      sB[lc][c]   = dbc[row * 80 + 48 + c];
      sC[lc][c]   = dbc[row * 80 + 64 + c];
    }
    __syncthreads();
    for (int lc = 0; lc < 64; ++lc) {
      float dlv = sdel[lc][dl];
      float xv  = sxc[lc][dl];
      float dA = exp2f(dlv * a2);
      h = fmaf(dA, h, dlv * xv * sB[lc][n]);
      float p = h * sC[lc][n];
      p += __shfl_xor(p, 1);
      p += __shfl_xor(p, 2);
      p += __shfl_xor(p, 4);
      p += __shfl_xor(p, 8);
      if (n == 0) {
        float zv = sz[lc][dl];
        float y = p + xv * dv;
        sy[lc][dl] = y * (zv / (1.f + __expf(-zv)));
      }
    }
    __syncthreads();
    #pragma unroll
    for (int k = 0; k < 4; ++k) {
      int i = tid + k * 256;
      int lc = i >> 4, c = i & 15;
      yg[(rowb + l0 + lc) * 1536 + d0 + c] = sy[lc][c];
    }
  }
}

// ---------------------------------------------------------------------------
// LayerNorm over last dim (768)
// ---------------------------------------------------------------------------
__global__ __launch_bounds__(256) void ln_f32(
    const float* __restrict__ in, const float* __restrict__ g,
    const float* __restrict__ b, float* __restrict__ out)
{
  int row = blockIdx.x * 4 + (threadIdx.x >> 6);
  int lane = threadIdx.x & 63;
  const float* xr = in + (size_t)row * DMODEL;
  float v[12];
  float s = 0.f, s2 = 0.f;
  #pragma unroll
  for (int i = 0; i < 12; ++i) {
    float t = xr[i * 64 + lane];
    v[i] = t; s += t; s2 = fmaf(t, t, s2);
  }
  #pragma unroll
  for (int off = 1; off < 64; off <<= 1) {
    s += __shfl_xor(s, off);
    s2 += __shfl_xor(s2, off);
  }
  float mean = s * (1.f / 768.f);
  float var = s2 * (1.f / 768.f) - mean * mean;
  float inv = rsqrtf(var + 1e-5f);
  float* orow = out + (size_t)row * DMODEL;
  #pragma unroll
  for (int i = 0; i < 12; ++i) {
    int c = i * 64 + lane;
    orow[c] = (v[i] - mean) * inv * g[c] + b[c];
  }
}

__global__ __launch_bounds__(256) void add3_f32(
    const float* __restrict__ a, const float* __restrict__ b,
    const float* __restrict__ c, float* __restrict__ o)
{
  int i = blockIdx.x * 256 + threadIdx.x;
  o[i] = a[i] + b[i] + c[i];
}

// ---------------------------------------------------------------------------
extern "C" void kernel_launch(void* const* d_in, const int* in_sizes, int n_in,
                              void* d_out, int out_size, void* d_ws, size_t ws_size,
                              hipStream_t stream)
{
  (void)in_sizes; (void)n_in; (void)out_size; (void)ws_size;
  const float* x         = (const float*)d_in[0];
  const float* qkv_w     = (const float*)d_in[1];
  const float* qkv_b     = (const float*)d_in[2];
  const float* att_out_w = (const float*)d_in[3];
  const float* att_out_b = (const float*)d_in[4];
  const float* conv3_w   = (const float*)d_in[5];
  const float* conv3_b   = (const float*)d_in[6];
  const float* conv5_w   = (const float*)d_in[7];
  const float* conv5_b   = (const float*)d_in[8];
  const float* conv7_w   = (const float*)d_in[9];
  const float* conv7_b   = (const float*)d_in[10];
  const float* gproj_w   = (const float*)d_in[11];
  const float* gproj_b   = (const float*)d_in[12];
  const float* lproj_w   = (const float*)d_in[13];
  const float* lproj_b   = (const float*)d_in[14];
  const float* fus_w     = (const float*)d_in[15];
  const float* fus_b     = (const float*)d_in[16];
  const float* glce_g    = (const float*)d_in[17];
  const float* glce_bb   = (const float*)d_in[18];
  const float* ssm_g     = (const float*)d_in[19];
  const float* ssm_bb    = (const float*)d_in[20];
  const float* in_w[2]   = {(const float*)d_in[21], (const float*)d_in[30]};
  const float* cw[2]     = {(const float*)d_in[22], (const float*)d_in[31]};
  const float* cb[2]     = {(const float*)d_in[23], (const float*)d_in[32]};
  const float* xp_w[2]   = {(const float*)d_in[24], (const float*)d_in[33]};
  const float* dt_w[2]   = {(const float*)d_in[25], (const float*)d_in[34]};
  const float* dt_b[2]   = {(const float*)d_in[26], (const float*)d_in[35]};
  const float* A_log[2]  = {(const float*)d_in[27], (const float*)d_in[36]};
  const float* Dp[2]     = {(const float*)d_in[28], (const float*)d_in[37]};
  const float* out_w[2]  = {(const float*)d_in[29], (const float*)d_in[38]};
  const float* ffn_g     = (const float*)d_in[39];
  const float* ffn_bb    = (const float*)d_in[40];
  const float* gate_w    = (const float*)d_in[41];
  const float* up_w      = (const float*)d_in[42];
  const float* down_w    = (const float*)d_in[43];

  float* ws = (float*)d_ws;
  size_t off = 0;
  const size_t M = 2048;
  auto take = [&](size_t n) { float* p = ws + off; off += n; return p; };
  float* QKV   = take(M * 2304);
  float* AO    = take(M * 768);
  float* AO2   = take(M * 768);
  float* GL    = take(M * 768);
  float* LOC   = take(M * 768);
  float* T1    = take(M * 768);
  float* X1    = take(M * 768);
  float* XN    = take(M * 768);
  float* XIZ   = take(M * 3072);
  float* XC    = take(M * 1536);
  float* DBC   = take(M * 80);
  float* DELTA = take(M * 1536);
  float* YG    = take(M * 1536);
  float* YF    = take(M * 768);
  float* YB    = take(M * 768);
  float* X2    = take(M * 768);
  float* GU    = XIZ;  // reuse (mamba finished before FFN)
  float* YFB[2] = {YF, YB};

  dim3 blk(256);

  // --- GLCE branch ---
  gemm_bf16<<<dim3(36, 32), blk, 0, stream>>>(x, 768, 0, qkv_w, qkv_b, nullptr,
                                              QKV, 2304, 0, 0, 2304, 768, 0, 0);
  attn_mfma<<<dim3(16, 16), blk, 0, stream>>>(QKV, AO);
  gemm_bf16<<<dim3(12, 32), blk, 0, stream>>>(AO, 768, 0, att_out_w, att_out_b, nullptr,
                                              AO2, 768, 0, 0, 768, 768, 0, 0);
  gemm_bf16<<<dim3(6, 32), blk, 0, stream>>>(AO2, 768, 0, gproj_w, gproj_b, nullptr,
                                             GL, 768, 0, 0, 384, 768, 0, 0);
  glce_conv<<<dim3(M * 768 / 256), blk, 0, stream>>>(x, conv3_w, conv3_b, conv5_w,
                                                     conv5_b, conv7_w, conv7_b, LOC);
  gemm_bf16<<<dim3(6, 32), blk, 0, stream>>>(LOC, 768, 0, lproj_w, lproj_b, nullptr,
                                             GL, 768, 384, 0, 384, 768, 0, 0);
  gemm_bf16<<<dim3(12, 32), blk, 0, stream>>>(GL, 768, 0, fus_w, fus_b, x,
                                              T1, 768, 0, 0, 768, 768, 0, 0);
  ln_f32<<<dim3(512), blk, 0, stream>>>(T1, glce_g, glce_bb, X1);

  // --- bidirectional mamba ---
  ln_f32<<<dim3(512), blk, 0, stream>>>(X1, ssm_g, ssm_bb, XN);
  for (int dir = 0; dir < 2; ++dir) {
    int flip = dir;
    gemm_bf16<<<dim3(48, 32), blk, 0, stream>>>(XN, 768, flip, in_w[dir], nullptr, nullptr,
                                                XIZ, 3072, 0, 0, 3072, 768, 0, 0);
    mamba_conv_f32<<<dim3(M * 1536 / 256), blk, 0, stream>>>(XIZ, cw[dir], cb[dir], XC);
    gemm_f32<<<dim3(2, 32), blk, 0, stream>>>(XC, 1536, 0, xp_w[dir], nullptr, nullptr,
                                              DBC, 80, 0, 0, 80, 1536, 0, 0);
    gemm_f32<<<dim3(24, 32), blk, 0, stream>>>(DBC, 80, 0, dt_w[dir], dt_b[dir], nullptr,
                                               DELTA, 1536, 0, 0, 1536, 48, 1, 0);
    mamba_scan_f32<<<dim3(192), blk, 0, stream>>>(DBC, DELTA, XC, XIZ, A_log[dir],
                                                  Dp[dir], YG);
    gemm_bf16<<<dim3(12, 32), blk, 0, stream>>>(YG, 1536, 0, out_w[dir], nullptr, nullptr,
                                                YFB[dir], 768, 0, flip, 768, 1536, 0, 0);
  }
  add3_f32<<<dim3(M * 768 / 256), blk, 0, stream>>>(X1, YF, YB, X2);

  // --- FFN ---
  ln_f32<<<dim3(512), blk, 0, stream>>>(X2, ffn_g, ffn_bb, XN);
  gemm_bf16<<<dim3(48, 32), blk, 0, stream>>>(XN, 768, 0, gate_w, nullptr, nullptr,
                                              GU, 3072, 0, 0, 3072, 768, 2, 0);
  gemm_bf16<<<dim3(48, 32), blk, 0, stream>>>(XN, 768, 0, up_w, nullptr, nullptr,
                                              GU, 3072, 0, 0, 3072, 768, 0, 1);
  gemm_bf16<<<dim3(12, 32), blk, 0, stream>>>(GU, 3072, 0, down_w, nullptr, X2,
                                              (float*)d_out, 768, 0, 0, 768, 3072, 0, 0);
}

// Round 4
// 1319.381 us; speedup vs baseline: 4.2071x; 1.2680x over previous
//
#include <hip/hip_runtime.h>
#include <math.h>

#define LSEQ 1024
#define DMODEL 768
#define NHEAD 8
#define HDIM 96
#define DI_ 1536
#define NST 16
#define DTR_ 48
#define FF_ 3072

typedef __attribute__((ext_vector_type(8))) short short8;
typedef __attribute__((ext_vector_type(4))) short short4_t;
typedef __attribute__((ext_vector_type(4))) float f32x4;

__device__ inline short f2bf(float f) {
  unsigned u = __builtin_bit_cast(unsigned, f);
  unsigned r = u + 0x7FFFu + ((u >> 16) & 1u);   // round-to-nearest-even
  return (short)(r >> 16);
}

// ---------------------------------------------------------------------------
// bf16 MFMA GEMM: C[m,n] = act( A[m,:] . W[n,:] + bias[n] ) (+residual / *=C)
// ---------------------------------------------------------------------------
__global__ __launch_bounds__(256) void gemm_bf16(
    const float* __restrict__ A, int lda, int flipA,
    const float* __restrict__ W,
    const float* __restrict__ bias,
    const float* __restrict__ residual,
    float* __restrict__ C, int ldc, int colOff, int flipC,
    int Ncols, int Kd, int act, int mulC)
{
  __shared__ short As[64][40];
  __shared__ short Ws[64][40];
  const int row0 = blockIdx.y * 64, col0 = blockIdx.x * 64;
  const int tid = threadIdx.x;
  const int w = tid >> 6, lane = tid & 63;
  const int m16 = lane & 15, kg = lane >> 4;

  f32x4 acc[4];
  #pragma unroll
  for (int i = 0; i < 4; ++i) acc[i] = (f32x4)(0.f);

  const int r8 = tid >> 3;
  const int kk = (tid & 7) << 2;
  const float* aptr[2];
  const float* wptr[2];
  int srow[2];
  #pragma unroll
  for (int u = 0; u < 2; ++u) {
    int gm = row0 + (u << 5) + r8;
    int bb = gm >> 10, ll = gm & 1023;
    if (flipA) ll = 1023 - ll;
    aptr[u] = A + (size_t)(bb * LSEQ + ll) * lda + kk;
    int gn = col0 + (u << 5) + r8;
    if (gn >= Ncols) gn = Ncols - 1;
    wptr[u] = W + (size_t)gn * Kd + kk;
    srow[u] = (u << 5) + r8;
  }

  for (int k0 = 0; k0 < Kd; k0 += 32) {
    #pragma unroll
    for (int u = 0; u < 2; ++u) {
      const int gk = k0 + kk;
      float4 av, wv;
      if (gk + 3 < Kd) {
        av = *(const float4*)(aptr[u] + k0);
        wv = *(const float4*)(wptr[u] + k0);
      } else {
        float ae[4], we[4];
        #pragma unroll
        for (int e = 0; e < 4; ++e) {
          bool in = (gk + e < Kd);
          ae[e] = in ? aptr[u][k0 + e] : 0.f;
          we[e] = in ? wptr[u][k0 + e] : 0.f;
        }
        av = make_float4(ae[0], ae[1], ae[2], ae[3]);
        wv = make_float4(we[0], we[1], we[2], we[3]);
      }
      short4_t ap = {f2bf(av.x), f2bf(av.y), f2bf(av.z), f2bf(av.w)};
      short4_t wp = {f2bf(wv.x), f2bf(wv.y), f2bf(wv.z), f2bf(wv.w)};
      *(short4_t*)&As[srow[u]][kk] = ap;
      *(short4_t*)&Ws[srow[u]][kk] = wp;
    }
    __syncthreads();
    short8 a = *(const short8*)&As[(w << 4) + m16][kg << 3];
    #pragma unroll
    for (int nt = 0; nt < 4; ++nt) {
      short8 b = *(const short8*)&Ws[(nt << 4) + m16][kg << 3];
      acc[nt] = __builtin_amdgcn_mfma_f32_16x16x32_bf16(a, b, acc[nt], 0, 0, 0);
    }
    __syncthreads();
  }

  #pragma unroll
  for (int nt = 0; nt < 4; ++nt) {
    int gn = col0 + (nt << 4) + m16;
    if (gn >= Ncols) continue;
    float bv = bias ? bias[gn] : 0.f;
    #pragma unroll
    for (int r = 0; r < 4; ++r) {
      int gm = row0 + (w << 4) + (kg << 2) + r;
      int bb = gm >> 10, ll = gm & 1023;
      if (flipC) ll = 1023 - ll;
      float v = acc[nt][r] + bv;
      if (act == 1) v = fmaxf(v, 0.f) + log1pf(__expf(-fabsf(v)));   // softplus
      else if (act == 2) v = v / (1.f + __expf(-v));                 // silu
      size_t idx = (size_t)(bb * LSEQ + ll) * ldc + colOff + gn;
      if (mulC) C[idx] *= v;
      else if (residual) C[idx] = residual[idx] + v;
      else C[idx] = v;
    }
  }
}

// ---------------------------------------------------------------------------
// fp32 GEMM (small, numerically sensitive xp/dt projections)
// ---------------------------------------------------------------------------
__global__ __launch_bounds__(256) void gemm_f32(
    const float* __restrict__ A, int lda, int flipA,
    const float* __restrict__ W,
    const float* __restrict__ bias,
    const float* __restrict__ residual,
    float* __restrict__ C, int ldc, int colOff, int flipC,
    int Ncols, int Kd, int act, int mulC)
{
  __shared__ float As[16][65];
  __shared__ float Bs[16][65];
  const int row0 = blockIdx.y * 64, col0 = blockIdx.x * 64;
  const int tid = threadIdx.x;
  const int tx = tid & 15, ty = tid >> 4;
  float acc[4][4] = {};
  const int lm = tid >> 2;
  const int lk = (tid & 3) << 2;
  int gmL = row0 + lm;
  int bbL = gmL >> 10, llL = gmL & 1023;
  if (flipA) llL = LSEQ - 1 - llL;
  const float* arow = A + (size_t)(bbL * LSEQ + llL) * lda;
  int gnL = col0 + lm;
  const bool wvalid = (gnL < Ncols);
  const float* wrow = W + (size_t)(wvalid ? gnL : 0) * Kd;

  for (int k0 = 0; k0 < Kd; k0 += 16) {
    #pragma unroll
    for (int u = 0; u < 4; ++u) {
      int kkk = k0 + lk + u;
      bool kin = (kkk < Kd);
      As[lk + u][lm] = kin ? arow[kkk] : 0.f;
      Bs[lk + u][lm] = (kin && wvalid) ? wrow[kkk] : 0.f;
    }
    __syncthreads();
    #pragma unroll
    for (int kkk = 0; kkk < 16; ++kkk) {
      float a[4], bv[4];
      #pragma unroll
      for (int i = 0; i < 4; ++i) a[i] = As[kkk][(ty << 2) + i];
      #pragma unroll
      for (int j = 0; j < 4; ++j) bv[j] = Bs[kkk][(tx << 2) + j];
      #pragma unroll
      for (int i = 0; i < 4; ++i)
        #pragma unroll
        for (int j = 0; j < 4; ++j)
          acc[i][j] = fmaf(a[i], bv[j], acc[i][j]);
    }
    __syncthreads();
  }

  #pragma unroll
  for (int i = 0; i < 4; ++i) {
    int gm = row0 + (ty << 2) + i;
    int bb = gm >> 10, ll = gm & 1023;
    if (flipC) ll = LSEQ - 1 - ll;
    size_t base = (size_t)(bb * LSEQ + ll) * ldc + colOff;
    #pragma unroll
    for (int j = 0; j < 4; ++j) {
      int gn = col0 + (tx << 2) + j;
      if (gn >= Ncols) continue;
      float v = acc[i][j];
      if (bias) v += bias[gn];
      if (act == 1) v = fmaxf(v, 0.f) + log1pf(__expf(-fabsf(v)));
      else if (act == 2) v = v / (1.f + __expf(-v));
      size_t idx = base + gn;
      if (mulC) C[idx] *= v;
      else if (residual) C[idx] = residual[idx] + v;
      else C[idx] = v;
    }
  }
}

// ---------------------------------------------------------------------------
// MFMA flash attention. One block = one (b,h) x 64 q rows; 4 waves x 16 rows.
// ---------------------------------------------------------------------------
__global__ __launch_bounds__(256) void attn_mfma(const float* __restrict__ qkv,
                                                 float* __restrict__ o)
{
  __shared__ short Ks[64][104];
  __shared__ short Vt[96][72];
  __shared__ short Ps[4][16][72];

  const int bh = blockIdx.y;
  const int b_ = bh >> 3, h = bh & 7;
  const int q0 = blockIdx.x * 64;
  const int tid = threadIdx.x;
  const int w = tid >> 6, lane = tid & 63;
  const int m16 = lane & 15, g4 = lane >> 4;

  const float sc2 = 0.10206207261596577f * 1.4426950408889634f;

  short8 qf[3];
  {
    const float* qrow = qkv + ((size_t)(b_ * LSEQ) + q0 + w * 16 + m16) * 2304 + h * HDIM;
    #pragma unroll
    for (int c = 0; c < 3; ++c) {
      float4 v0 = *(const float4*)(qrow + c * 32 + g4 * 8);
      float4 v1 = *(const float4*)(qrow + c * 32 + g4 * 8 + 4);
      qf[c] = short8{f2bf(v0.x), f2bf(v0.y), f2bf(v0.z), f2bf(v0.w),
                     f2bf(v1.x), f2bf(v1.y), f2bf(v1.z), f2bf(v1.w)};
    }
  }

  float m_run[4], l_run[4];
  #pragma unroll
  for (int r = 0; r < 4; ++r) { m_run[r] = -INFINITY; l_run[r] = 0.f; }
  f32x4 oacc[6];
  #pragma unroll
  for (int ct = 0; ct < 6; ++ct) oacc[ct] = (f32x4)(0.f);

  const int kr = tid >> 2;
  const int cc = (tid & 3) * 24;

  for (int t = 0; t < LSEQ / 64; ++t) {
    const int k0 = t * 64;
    __syncthreads();
    {
      const float* kp = qkv + ((size_t)(b_ * LSEQ) + k0 + kr) * 2304 + DMODEL + h * HDIM + cc;
      const float* vp = kp + DMODEL;
      #pragma unroll
      for (int u = 0; u < 6; ++u) {
        float4 kv = *(const float4*)(kp + u * 4);
        *(short4_t*)&Ks[kr][cc + u * 4] =
            short4_t{f2bf(kv.x), f2bf(kv.y), f2bf(kv.z), f2bf(kv.w)};
        float4 vv = *(const float4*)(vp + u * 4);
        Vt[cc + u * 4 + 0][kr] = f2bf(vv.x);
        Vt[cc + u * 4 + 1][kr] = f2bf(vv.y);
        Vt[cc + u * 4 + 2][kr] = f2bf(vv.z);
        Vt[cc + u * 4 + 3][kr] = f2bf(vv.w);
      }
    }
    __syncthreads();

    f32x4 sacc[4];
    #pragma unroll
    for (int kt = 0; kt < 4; ++kt) sacc[kt] = (f32x4)(0.f);
    #pragma unroll
    for (int c = 0; c < 3; ++c) {
      #pragma unroll
      for (int kt = 0; kt < 4; ++kt) {
        short8 bfrag = *(const short8*)&Ks[kt * 16 + m16][c * 32 + g4 * 8];
        sacc[kt] = __builtin_amdgcn_mfma_f32_16x16x32_bf16(qf[c], bfrag, sacc[kt], 0, 0, 0);
      }
    }

    #pragma unroll
    for (int r = 0; r < 4; ++r) {
      float s0 = sacc[0][r] * sc2, s1 = sacc[1][r] * sc2;
      float s2v = sacc[2][r] * sc2, s3 = sacc[3][r] * sc2;
      float mv = fmaxf(fmaxf(s0, s1), fmaxf(s2v, s3));
      mv = fmaxf(mv, __shfl_xor(mv, 1));
      mv = fmaxf(mv, __shfl_xor(mv, 2));
      mv = fmaxf(mv, __shfl_xor(mv, 4));
      mv = fmaxf(mv, __shfl_xor(mv, 8));
      float mnew = fmaxf(m_run[r], mv);
      float scale = exp2f(m_run[r] - mnew);
      float p0 = exp2f(s0 - mnew), p1 = exp2f(s1 - mnew);
      float p2 = exp2f(s2v - mnew), p3 = exp2f(s3 - mnew);
      short* pr = &Ps[w][g4 * 4 + r][m16];
      pr[0]  = f2bf(p0);
      pr[16] = f2bf(p1);
      pr[32] = f2bf(p2);
      pr[48] = f2bf(p3);
      float ps = p0 + p1 + p2 + p3;
      ps += __shfl_xor(ps, 1);
      ps += __shfl_xor(ps, 2);
      ps += __shfl_xor(ps, 4);
      ps += __shfl_xor(ps, 8);
      l_run[r] = l_run[r] * scale + ps;
      m_run[r] = mnew;
      #pragma unroll
      for (int ct = 0; ct < 6; ++ct) oacc[ct][r] *= scale;
    }

    #pragma unroll
    for (int kc = 0; kc < 2; ++kc) {
      short8 pa = *(const short8*)&Ps[w][m16][kc * 32 + g4 * 8];
      #pragma unroll
      for (int ct = 0; ct < 6; ++ct) {
        short8 vb = *(const short8*)&Vt[ct * 16 + m16][kc * 32 + g4 * 8];
        oacc[ct] = __builtin_amdgcn_mfma_f32_16x16x32_bf16(pa, vb, oacc[ct], 0, 0, 0);
      }
    }
  }

  #pragma unroll
  for (int r = 0; r < 4; ++r) {
    float inv = 1.f / l_run[r];
    float* orow = o + ((size_t)(b_ * LSEQ) + q0 + w * 16 + g4 * 4 + r) * DMODEL + h * HDIM;
    #pragma unroll
    for (int ct = 0; ct < 6; ++ct)
      orow[ct * 16 + m16] = oacc[ct][r] * inv;
  }
}

// ---------------------------------------------------------------------------
// GLCE convs (kernels 3/5/7, 3 in-ch per out-ch, exact gelu)
// ---------------------------------------------------------------------------
__global__ __launch_bounds__(256) void glce_conv(
    const float* __restrict__ x,
    const float* __restrict__ w3, const float* __restrict__ b3,
    const float* __restrict__ w5, const float* __restrict__ b5,
    const float* __restrict__ w7, const float* __restrict__ b7,
    float* __restrict__ loc)
{
  int idx = blockIdx.x * 256 + threadIdx.x;
  int c = idx % DMODEL;
  int bl = idx / DMODEL;
  int l = bl & 1023, b_ = bl >> 10;
  int cs = c >> 8, ch = c & 255;
  const float* wp; float bias; int kt, pad;
  if (cs == 0)      { wp = w3 + ch * 9;  bias = b3[ch]; kt = 3; pad = 1; }
  else if (cs == 1) { wp = w5 + ch * 15; bias = b5[ch]; kt = 5; pad = 2; }
  else              { wp = w7 + ch * 21; bias = b7[ch]; kt = 7; pad = 3; }
  float acc = bias;
  const float* xb = x + (size_t)(b_ * LSEQ) * DMODEL;
  for (int i = 0; i < 3; ++i) {
    int d = 3 * ch + i;
    for (int t = 0; t < kt; ++t) {
      int ls = l - pad + t;
      if (ls >= 0 && ls < LSEQ)
        acc = fmaf(xb[(size_t)ls * DMODEL + d], wp[i * kt + t], acc);
    }
  }
  loc[idx] = 0.5f * acc * (1.f + erff(acc * 0.7071067811865475f));
}

// ---------------------------------------------------------------------------
// Mamba depthwise causal conv (K=4) + silu
// ---------------------------------------------------------------------------
__global__ __launch_bounds__(256) void mamba_conv_f32(
    const float* __restrict__ xiz, const float* __restrict__ cw,
    const float* __restrict__ cb, float* __restrict__ xc)
{
  int idx = blockIdx.x * 256 + threadIdx.x;
  int d = idx % DI_;
  int bl = idx / DI_;
  int l = bl & 1023, b_ = bl >> 10;
  const float* w = cw + d * 4;
  float acc = cb[d];
  #pragma unroll
  for (int t = 0; t < 4; ++t) {
    int ls = l - 3 + t;
    if (ls >= 0)
      acc = fmaf(xiz[((size_t)(b_ * LSEQ + ls)) * 3072 + d], w[t], acc);
  }
  xc[idx] = acc / (1.f + __expf(-acc));
}

// ---------------------------------------------------------------------------
// Chunked selective scan. CHUNK=64, NCHUNK=16.
// Pass A: per-(b,d,n,chunk) local scan (h0=0) -> S, and decay product P.
// Pass B: per-(b,d,n) prefix over 16 chunks -> chunk-entry states HI.
// Pass C: re-run local scan seeded with HI, y = C.h (+xc*D), *silu(z) -> yg.
// Index layout for S/P/HI: ((b*1536+d)*16 + chunk)*16 + n.
// ---------------------------------------------------------------------------
__global__ __launch_bounds__(256) void mamba_scan_part(
    const float* __restrict__ dbc, const float* __restrict__ delta,
    const float* __restrict__ xc, const float* __restrict__ A_log,
    float* __restrict__ SS, float* __restrict__ PP)
{
  const int bc = blockIdx.x;
  const int b_ = bc / (96 * 16);
  const int rem = bc % (96 * 16);
  const int d0 = (rem >> 4) << 4;
  const int ck = rem & 15;
  const int tid = threadIdx.x;
  const int dl = tid >> 4, n = tid & 15;
  const int d = d0 + dl;
  const float a2 = -__expf(A_log[d * 16 + n]) * 1.4426950408889634f;

  __shared__ float sdel[64][16];
  __shared__ float sxc[64][16];
  __shared__ float sB[64][16];
  const size_t rowb = (size_t)b_ * LSEQ + ck * 64;

  #pragma unroll
  for (int k = 0; k < 4; ++k) {
    int i = tid + k * 256;
    int lc = i >> 4, c = i & 15;
    size_t row = rowb + lc;
    sdel[lc][c] = delta[row * 1536 + d0 + c];
    sxc[lc][c]  = xc[row * 1536 + d0 + c];
    sB[lc][c]   = dbc[row * 80 + 48 + c];
  }
  __syncthreads();

  float h = 0.f, sumd = 0.f;
  for (int lc = 0; lc < 64; ++lc) {
    float dlv = sdel[lc][dl];
    float xv  = sxc[lc][dl];
    float dA = exp2f(dlv * a2);
    h = fmaf(dA, h, dlv * xv * sB[lc][n]);
    sumd += dlv;
  }
  size_t idx = (((size_t)b_ * 1536 + d) * 16 + ck) * 16 + n;
  SS[idx] = h;
  PP[idx] = exp2f(a2 * sumd);
}

__global__ __launch_bounds__(256) void mamba_scan_comb(
    const float* __restrict__ SS, const float* __restrict__ PP,
    float* __restrict__ HI)
{
  int t = blockIdx.x * 256 + threadIdx.x;       // 0 .. 49151 = (b*1536+d)*16+n
  size_t base = (size_t)(t >> 4) * 256 + (t & 15);
  float run = 0.f;
  #pragma unroll
  for (int c = 0; c < 16; ++c) {
    size_t idx = base + c * 16;
    HI[idx] = run;
    run = fmaf(PP[idx], run, SS[idx]);
  }
}

__global__ __launch_bounds__(256) void mamba_scan_fin(
    const float* __restrict__ dbc, const float* __restrict__ delta,
    const float* __restrict__ xc, const float* __restrict__ xiz,
    const float* __restrict__ A_log, const float* __restrict__ Dp,
    const float* __restrict__ HI, float* __restrict__ yg)
{
  const int bc = blockIdx.x;
  const int b_ = bc / (96 * 16);
  const int rem = bc % (96 * 16);
  const int d0 = (rem >> 4) << 4;
  const int ck = rem & 15;
  const int tid = threadIdx.x;
  const int dl = tid >> 4, n = tid & 15;
  const int d = d0 + dl;
  const float a2 = -__expf(A_log[d * 16 + n]) * 1.4426950408889634f;
  const float dv = Dp[d];

  __shared__ float sdel[64][16];
  __shared__ float sxc[64][16];
  __shared__ float sz[64][16];
  __shared__ float sB[64][16];
  __shared__ float sC[64][16];
  __shared__ float sy[64][16];
  const size_t rowb = (size_t)b_ * LSEQ + ck * 64;

  #pragma unroll
  for (int k = 0; k < 4; ++k) {
    int i = tid + k * 256;
    int lc = i >> 4, c = i & 15;
    size_t row = rowb + lc;
    sdel[lc][c] = delta[row * 1536 + d0 + c];
    sxc[lc][c]  = xc[row * 1536 + d0 + c];
    sz[lc][c]   = xiz[row * 3072 + 1536 + d0 + c];
    sB[lc][c]   = dbc[row * 80 + 48 + c];
    sC[lc][c]   = dbc[row * 80 + 64 + c];
  }
  __syncthreads();

  float h = HI[(((size_t)b_ * 1536 + d) * 16 + ck) * 16 + n];
  for (int lc = 0; lc < 64; ++lc) {
    float dlv = sdel[lc][dl];
    float xv  = sxc[lc][dl];
    float dA = exp2f(dlv * a2);
    h = fmaf(dA, h, dlv * xv * sB[lc][n]);
    float p = h * sC[lc][n];
    p += __shfl_xor(p, 1);
    p += __shfl_xor(p, 2);
    p += __shfl_xor(p, 4);
    p += __shfl_xor(p, 8);
    if (n == 0) {
      float zv = sz[lc][dl];
      float y = p + xv * dv;
      sy[lc][dl] = y * (zv / (1.f + __expf(-zv)));
    }
  }
  __syncthreads();
  #pragma unroll
  for (int k = 0; k < 4; ++k) {
    int i = tid + k * 256;
    int lc = i >> 4, c = i & 15;
    yg[(rowb + lc) * 1536 + d0 + c] = sy[lc][c];
  }
}

// ---------------------------------------------------------------------------
// LayerNorm over last dim (768)
// ---------------------------------------------------------------------------
__global__ __launch_bounds__(256) void ln_f32(
    const float* __restrict__ in, const float* __restrict__ g,
    const float* __restrict__ b, float* __restrict__ out)
{
  int row = blockIdx.x * 4 + (threadIdx.x >> 6);
  int lane = threadIdx.x & 63;
  const float* xr = in + (size_t)row * DMODEL;
  float v[12];
  float s = 0.f, s2 = 0.f;
  #pragma unroll
  for (int i = 0; i < 12; ++i) {
    float t = xr[i * 64 + lane];
    v[i] = t; s += t; s2 = fmaf(t, t, s2);
  }
  #pragma unroll
  for (int off = 1; off < 64; off <<= 1) {
    s += __shfl_xor(s, off);
    s2 += __shfl_xor(s2, off);
  }
  float mean = s * (1.f / 768.f);
  float var = s2 * (1.f / 768.f) - mean * mean;
  float inv = rsqrtf(var + 1e-5f);
  float* orow = out + (size_t)row * DMODEL;
  #pragma unroll
  for (int i = 0; i < 12; ++i) {
    int c = i * 64 + lane;
    orow[c] = (v[i] - mean) * inv * g[c] + b[c];
  }
}

__global__ __launch_bounds__(256) void add3_f32(
    const float* __restrict__ a, const float* __restrict__ b,
    const float* __restrict__ c, float* __restrict__ o)
{
  int i = blockIdx.x * 256 + threadIdx.x;
  o[i] = a[i] + b[i] + c[i];
}

// ---------------------------------------------------------------------------
extern "C" void kernel_launch(void* const* d_in, const int* in_sizes, int n_in,
                              void* d_out, int out_size, void* d_ws, size_t ws_size,
                              hipStream_t stream)
{
  (void)in_sizes; (void)n_in; (void)out_size; (void)ws_size;
  const float* x         = (const float*)d_in[0];
  const float* qkv_w     = (const float*)d_in[1];
  const float* qkv_b     = (const float*)d_in[2];
  const float* att_out_w = (const float*)d_in[3];
  const float* att_out_b = (const float*)d_in[4];
  const float* conv3_w   = (const float*)d_in[5];
  const float* conv3_b   = (const float*)d_in[6];
  const float* conv5_w   = (const float*)d_in[7];
  const float* conv5_b   = (const float*)d_in[8];
  const float* conv7_w   = (const float*)d_in[9];
  const float* conv7_b   = (const float*)d_in[10];
  const float* gproj_w   = (const float*)d_in[11];
  const float* gproj_b   = (const float*)d_in[12];
  const float* lproj_w   = (const float*)d_in[13];
  const float* lproj_b   = (const float*)d_in[14];
  const float* fus_w     = (const float*)d_in[15];
  const float* fus_b     = (const float*)d_in[16];
  const float* glce_g    = (const float*)d_in[17];
  const float* glce_bb   = (const float*)d_in[18];
  const float* ssm_g     = (const float*)d_in[19];
  const float* ssm_bb    = (const float*)d_in[20];
  const float* in_w[2]   = {(const float*)d_in[21], (const float*)d_in[30]};
  const float* cw[2]     = {(const float*)d_in[22], (const float*)d_in[31]};
  const float* cb[2]     = {(const float*)d_in[23], (const float*)d_in[32]};
  const float* xp_w[2]   = {(const float*)d_in[24], (const float*)d_in[33]};
  const float* dt_w[2]   = {(const float*)d_in[25], (const float*)d_in[34]};
  const float* dt_b[2]   = {(const float*)d_in[26], (const float*)d_in[35]};
  const float* A_log[2]  = {(const float*)d_in[27], (const float*)d_in[36]};
  const float* Dp[2]     = {(const float*)d_in[28], (const float*)d_in[37]};
  const float* out_w[2]  = {(const float*)d_in[29], (const float*)d_in[38]};
  const float* ffn_g     = (const float*)d_in[39];
  const float* ffn_bb    = (const float*)d_in[40];
  const float* gate_w    = (const float*)d_in[41];
  const float* up_w      = (const float*)d_in[42];
  const float* down_w    = (const float*)d_in[43];

  float* ws = (float*)d_ws;
  size_t off = 0;
  const size_t M = 2048;
  auto take = [&](size_t n) { float* p = ws + off; off += n; return p; };
  float* QKV   = take(M * 2304);
  float* AO    = take(M * 768);
  float* AO2   = take(M * 768);
  float* GL    = take(M * 768);
  float* LOC   = take(M * 768);
  float* T1    = take(M * 768);
  float* X1    = take(M * 768);
  float* XN    = take(M * 768);
  float* XIZ   = take(M * 3072);
  float* XC    = take(M * 1536);
  float* DBC   = take(M * 80);
  float* DELTA = take(M * 1536);
  float* YG    = take(M * 1536);
  float* YF    = take(M * 768);
  float* YB    = take(M * 768);
  float* X2    = take(M * 768);
  float* SS    = take(2 * 1536 * 16 * 16);
  float* PP    = take(2 * 1536 * 16 * 16);
  float* HI    = take(2 * 1536 * 16 * 16);
  float* GU    = XIZ;  // reuse (mamba finished before FFN)
  float* YFB[2] = {YF, YB};

  dim3 blk(256);

  // --- GLCE branch ---
  gemm_bf16<<<dim3(36, 32), blk, 0, stream>>>(x, 768, 0, qkv_w, qkv_b, nullptr,
                                              QKV, 2304, 0, 0, 2304, 768, 0, 0);
  attn_mfma<<<dim3(16, 16), blk, 0, stream>>>(QKV, AO);
  gemm_bf16<<<dim3(12, 32), blk, 0, stream>>>(AO, 768, 0, att_out_w, att_out_b, nullptr,
                                              AO2, 768, 0, 0, 768, 768, 0, 0);
  gemm_bf16<<<dim3(6, 32), blk, 0, stream>>>(AO2, 768, 0, gproj_w, gproj_b, nullptr,
                                             GL, 768, 0, 0, 384, 768, 0, 0);
  glce_conv<<<dim3(M * 768 / 256), blk, 0, stream>>>(x, conv3_w, conv3_b, conv5_w,
                                                     conv5_b, conv7_w, conv7_b, LOC);
  gemm_bf16<<<dim3(6, 32), blk, 0, stream>>>(LOC, 768, 0, lproj_w, lproj_b, nullptr,
                                             GL, 768, 384, 0, 384, 768, 0, 0);
  gemm_bf16<<<dim3(12, 32), blk, 0, stream>>>(GL, 768, 0, fus_w, fus_b, x,
                                              T1, 768, 0, 0, 768, 768, 0, 0);
  ln_f32<<<dim3(512), blk, 0, stream>>>(T1, glce_g, glce_bb, X1);

  // --- bidirectional mamba ---
  ln_f32<<<dim3(512), blk, 0, stream>>>(X1, ssm_g, ssm_bb, XN);
  for (int dir = 0; dir < 2; ++dir) {
    int flip = dir;
    gemm_bf16<<<dim3(48, 32), blk, 0, stream>>>(XN, 768, flip, in_w[dir], nullptr, nullptr,
                                                XIZ, 3072, 0, 0, 3072, 768, 0, 0);
    mamba_conv_f32<<<dim3(M * 1536 / 256), blk, 0, stream>>>(XIZ, cw[dir], cb[dir], XC);
    gemm_f32<<<dim3(2, 32), blk, 0, stream>>>(XC, 1536, 0, xp_w[dir], nullptr, nullptr,
                                              DBC, 80, 0, 0, 80, 1536, 0, 0);
    gemm_f32<<<dim3(24, 32), blk, 0, stream>>>(DBC, 80, 0, dt_w[dir], dt_b[dir], nullptr,
                                               DELTA, 1536, 0, 0, 1536, 48, 1, 0);
    mamba_scan_part<<<dim3(3072), blk, 0, stream>>>(DBC, DELTA, XC, A_log[dir], SS, PP);
    mamba_scan_comb<<<dim3(192), blk, 0, stream>>>(SS, PP, HI);
    mamba_scan_fin<<<dim3(3072), blk, 0, stream>>>(DBC, DELTA, XC, XIZ, A_log[dir],
                                                   Dp[dir], HI, YG);
    gemm_bf16<<<dim3(12, 32), blk, 0, stream>>>(YG, 1536, 0, out_w[dir], nullptr, nullptr,
                                                YFB[dir], 768, 0, flip, 768, 1536, 0, 0);
  }
  add3_f32<<<dim3(M * 768 / 256), blk, 0, stream>>>(X1, YF, YB, X2);

  // --- FFN ---
  ln_f32<<<dim3(512), blk, 0, stream>>>(X2, ffn_g, ffn_bb, XN);
  gemm_bf16<<<dim3(48, 32), blk, 0, stream>>>(XN, 768, 0, gate_w, nullptr, nullptr,
                                              GU, 3072, 0, 0, 3072, 768, 2, 0);
  gemm_bf16<<<dim3(48, 32), blk, 0, stream>>>(XN, 768, 0, up_w, nullptr, nullptr,
                                              GU, 3072, 0, 0, 3072, 768, 0, 1);
  gemm_bf16<<<dim3(12, 32), blk, 0, stream>>>(GU, 3072, 0, down_w, nullptr, X2,
                                              (float*)d_out, 768, 0, 0, 768, 3072, 0, 0);
}

// Round 5
// 1026.062 us; speedup vs baseline: 5.4097x; 1.2859x over previous
//
#include <hip/hip_runtime.h>
#include <math.h>

#define LSEQ 1024
#define DMODEL 768
#define NHEAD 8
#define HDIM 96
#define DI_ 1536
#define NST 16
#define DTR_ 48
#define FF_ 3072

typedef __attribute__((ext_vector_type(8))) short short8;
typedef __attribute__((ext_vector_type(4))) short short4_t;
typedef __attribute__((ext_vector_type(4))) float f32x4;

__device__ inline short f2bf(float f) {
  unsigned u = __builtin_bit_cast(unsigned, f);
  unsigned r = u + 0x7FFFu + ((u >> 16) & 1u);   // round-to-nearest-even
  return (short)(r >> 16);
}

// ---------------------------------------------------------------------------
// bf16 MFMA GEMM: C[m,n] = act( A[m,:] . W[n,:] + bias[n] ) (+residual / *=C)
// ---------------------------------------------------------------------------
__global__ __launch_bounds__(256) void gemm_bf16(
    const float* __restrict__ A, int lda, int flipA,
    const float* __restrict__ W,
    const float* __restrict__ bias,
    const float* __restrict__ residual,
    float* __restrict__ C, int ldc, int colOff, int flipC,
    int Ncols, int Kd, int act, int mulC)
{
  __shared__ short As[64][40];
  __shared__ short Ws[64][40];
  const int row0 = blockIdx.y * 64, col0 = blockIdx.x * 64;
  const int tid = threadIdx.x;
  const int w = tid >> 6, lane = tid & 63;
  const int m16 = lane & 15, kg = lane >> 4;

  f32x4 acc[4];
  #pragma unroll
  for (int i = 0; i < 4; ++i) acc[i] = (f32x4)(0.f);

  const int r8 = tid >> 3;
  const int kk = (tid & 7) << 2;
  const float* aptr[2];
  const float* wptr[2];
  int srow[2];
  #pragma unroll
  for (int u = 0; u < 2; ++u) {
    int gm = row0 + (u << 5) + r8;
    int bb = gm >> 10, ll = gm & 1023;
    if (flipA) ll = 1023 - ll;
    aptr[u] = A + (size_t)(bb * LSEQ + ll) * lda + kk;
    int gn = col0 + (u << 5) + r8;
    if (gn >= Ncols) gn = Ncols - 1;
    wptr[u] = W + (size_t)gn * Kd + kk;
    srow[u] = (u << 5) + r8;
  }

  for (int k0 = 0; k0 < Kd; k0 += 32) {
    #pragma unroll
    for (int u = 0; u < 2; ++u) {
      const int gk = k0 + kk;
      float4 av, wv;
      if (gk + 3 < Kd) {
        av = *(const float4*)(aptr[u] + k0);
        wv = *(const float4*)(wptr[u] + k0);
      } else {
        float ae[4], we[4];
        #pragma unroll
        for (int e = 0; e < 4; ++e) {
          bool in = (gk + e < Kd);
          ae[e] = in ? aptr[u][k0 + e] : 0.f;
          we[e] = in ? wptr[u][k0 + e] : 0.f;
        }
        av = make_float4(ae[0], ae[1], ae[2], ae[3]);
        wv = make_float4(we[0], we[1], we[2], we[3]);
      }
      short4_t ap = {f2bf(av.x), f2bf(av.y), f2bf(av.z), f2bf(av.w)};
      short4_t wp = {f2bf(wv.x), f2bf(wv.y), f2bf(wv.z), f2bf(wv.w)};
      *(short4_t*)&As[srow[u]][kk] = ap;
      *(short4_t*)&Ws[srow[u]][kk] = wp;
    }
    __syncthreads();
    short8 a = *(const short8*)&As[(w << 4) + m16][kg << 3];
    #pragma unroll
    for (int nt = 0; nt < 4; ++nt) {
      short8 b = *(const short8*)&Ws[(nt << 4) + m16][kg << 3];
      acc[nt] = __builtin_amdgcn_mfma_f32_16x16x32_bf16(a, b, acc[nt], 0, 0, 0);
    }
    __syncthreads();
  }

  #pragma unroll
  for (int nt = 0; nt < 4; ++nt) {
    int gn = col0 + (nt << 4) + m16;
    if (gn >= Ncols) continue;
    float bv = bias ? bias[gn] : 0.f;
    #pragma unroll
    for (int r = 0; r < 4; ++r) {
      int gm = row0 + (w << 4) + (kg << 2) + r;
      int bb = gm >> 10, ll = gm & 1023;
      if (flipC) ll = 1023 - ll;
      float v = acc[nt][r] + bv;
      if (act == 1) v = fmaxf(v, 0.f) + log1pf(__expf(-fabsf(v)));   // softplus
      else if (act == 2) v = v / (1.f + __expf(-v));                 // silu
      size_t idx = (size_t)(bb * LSEQ + ll) * ldc + colOff + gn;
      if (mulC) C[idx] *= v;
      else if (residual) C[idx] = residual[idx] + v;
      else C[idx] = v;
    }
  }
}

// ---------------------------------------------------------------------------
// fp32 GEMM (kept for the dt projection: K=48, N=1536, plenty of blocks)
// ---------------------------------------------------------------------------
__global__ __launch_bounds__(256) void gemm_f32(
    const float* __restrict__ A, int lda, int flipA,
    const float* __restrict__ W,
    const float* __restrict__ bias,
    const float* __restrict__ residual,
    float* __restrict__ C, int ldc, int colOff, int flipC,
    int Ncols, int Kd, int act, int mulC)
{
  __shared__ float As[16][65];
  __shared__ float Bs[16][65];
  const int row0 = blockIdx.y * 64, col0 = blockIdx.x * 64;
  const int tid = threadIdx.x;
  const int tx = tid & 15, ty = tid >> 4;
  float acc[4][4] = {};
  const int lm = tid >> 2;
  const int lk = (tid & 3) << 2;
  int gmL = row0 + lm;
  int bbL = gmL >> 10, llL = gmL & 1023;
  if (flipA) llL = LSEQ - 1 - llL;
  const float* arow = A + (size_t)(bbL * LSEQ + llL) * lda;
  int gnL = col0 + lm;
  const bool wvalid = (gnL < Ncols);
  const float* wrow = W + (size_t)(wvalid ? gnL : 0) * Kd;

  for (int k0 = 0; k0 < Kd; k0 += 16) {
    #pragma unroll
    for (int u = 0; u < 4; ++u) {
      int kkk = k0 + lk + u;
      bool kin = (kkk < Kd);
      As[lk + u][lm] = kin ? arow[kkk] : 0.f;
      Bs[lk + u][lm] = (kin && wvalid) ? wrow[kkk] : 0.f;
    }
    __syncthreads();
    #pragma unroll
    for (int kkk = 0; kkk < 16; ++kkk) {
      float a[4], bv[4];
      #pragma unroll
      for (int i = 0; i < 4; ++i) a[i] = As[kkk][(ty << 2) + i];
      #pragma unroll
      for (int j = 0; j < 4; ++j) bv[j] = Bs[kkk][(tx << 2) + j];
      #pragma unroll
      for (int i = 0; i < 4; ++i)
        #pragma unroll
        for (int j = 0; j < 4; ++j)
          acc[i][j] = fmaf(a[i], bv[j], acc[i][j]);
    }
    __syncthreads();
  }

  #pragma unroll
  for (int i = 0; i < 4; ++i) {
    int gm = row0 + (ty << 2) + i;
    int bb = gm >> 10, ll = gm & 1023;
    if (flipC) ll = LSEQ - 1 - ll;
    size_t base = (size_t)(bb * LSEQ + ll) * ldc + colOff;
    #pragma unroll
    for (int j = 0; j < 4; ++j) {
      int gn = col0 + (tx << 2) + j;
      if (gn >= Ncols) continue;
      float v = acc[i][j];
      if (bias) v += bias[gn];
      if (act == 1) v = fmaxf(v, 0.f) + log1pf(__expf(-fabsf(v)));
      else if (act == 2) v = v / (1.f + __expf(-v));
      size_t idx = base + gn;
      if (mulC) C[idx] *= v;
      else if (residual) C[idx] = residual[idx] + v;
      else C[idx] = v;
    }
  }
}

// ---------------------------------------------------------------------------
// Split-K fp32 GEMM for the skinny xp projection (M=2048, N=80, K=1536).
// grid (32 row-tiles, 8 K-splits). Block: 64 rows x 80 cols, K-chunk 192.
// Thread = 4 rows x 5 cols. Partials to PART[ks][row][80].
// ---------------------------------------------------------------------------
#define XP_KSPLIT 8
#define XP_KCH 192
__global__ __launch_bounds__(256) void xp_part(
    const float* __restrict__ A,            // XC 2048x1536
    const float* __restrict__ W,            // 80x1536
    float* __restrict__ PART)
{
  __shared__ float As[64][34];
  __shared__ float Ws[80][34];
  const int tid = threadIdx.x;
  const int row0 = blockIdx.x * 64;
  const int kbase = blockIdx.y * XP_KCH;
  const int ty = tid >> 4, tx = tid & 15;

  float acc[4][5] = {};

  for (int ch = 0; ch < XP_KCH; ch += 32) {
    const int gk = kbase + ch;
    __syncthreads();
    #pragma unroll
    for (int u = 0; u < 2; ++u) {
      int i = tid + u * 256;
      int r = i >> 3, k4 = (i & 7) << 2;
      *(float4*)&As[r][k4] = *(const float4*)&A[(size_t)(row0 + r) * 1536 + gk + k4];
    }
    #pragma unroll
    for (int u = 0; u < 3; ++u) {
      int j = tid + u * 256;
      if (j < 640) {
        int c = j >> 3, k4 = (j & 7) << 2;
        *(float4*)&Ws[c][k4] = *(const float4*)&W[(size_t)c * 1536 + gk + k4];
      }
    }
    __syncthreads();
    #pragma unroll
    for (int k = 0; k < 32; k += 2) {
      float2 a2[4], w2[5];
      #pragma unroll
      for (int i = 0; i < 4; ++i) a2[i] = *(const float2*)&As[ty + 16 * i][k];
      #pragma unroll
      for (int j = 0; j < 5; ++j) w2[j] = *(const float2*)&Ws[tx + 16 * j][k];
      #pragma unroll
      for (int i = 0; i < 4; ++i)
        #pragma unroll
        for (int j = 0; j < 5; ++j) {
          acc[i][j] = fmaf(a2[i].x, w2[j].x, acc[i][j]);
          acc[i][j] = fmaf(a2[i].y, w2[j].y, acc[i][j]);
        }
    }
  }

  float* pbase = PART + (size_t)blockIdx.y * 2048 * 80;
  #pragma unroll
  for (int i = 0; i < 4; ++i) {
    int gr = row0 + ty + 16 * i;
    #pragma unroll
    for (int j = 0; j < 5; ++j)
      pbase[(size_t)gr * 80 + tx + 16 * j] = acc[i][j];
  }
}

__global__ __launch_bounds__(256) void xp_reduce(
    const float* __restrict__ PART, float* __restrict__ DBC)
{
  int t = blockIdx.x * 256 + threadIdx.x;   // 0 .. 2048*80-1
  float s = 0.f;
  #pragma unroll
  for (int ks = 0; ks < XP_KSPLIT; ++ks)
    s += PART[(size_t)ks * 2048 * 80 + t];
  DBC[t] = s;
}

// ---------------------------------------------------------------------------
// MFMA flash attention. One block = one (b,h) x 64 q rows; 4 waves x 16 rows.
// ---------------------------------------------------------------------------
__global__ __launch_bounds__(256) void attn_mfma(const float* __restrict__ qkv,
                                                 float* __restrict__ o)
{
  __shared__ short Ks[64][104];
  __shared__ short Vt[96][72];
  __shared__ short Ps[4][16][72];

  const int bh = blockIdx.y;
  const int b_ = bh >> 3, h = bh & 7;
  const int q0 = blockIdx.x * 64;
  const int tid = threadIdx.x;
  const int w = tid >> 6, lane = tid & 63;
  const int m16 = lane & 15, g4 = lane >> 4;

  const float sc2 = 0.10206207261596577f * 1.4426950408889634f;

  short8 qf[3];
  {
    const float* qrow = qkv + ((size_t)(b_ * LSEQ) + q0 + w * 16 + m16) * 2304 + h * HDIM;
    #pragma unroll
    for (int c = 0; c < 3; ++c) {
      float4 v0 = *(const float4*)(qrow + c * 32 + g4 * 8);
      float4 v1 = *(const float4*)(qrow + c * 32 + g4 * 8 + 4);
      qf[c] = short8{f2bf(v0.x), f2bf(v0.y), f2bf(v0.z), f2bf(v0.w),
                     f2bf(v1.x), f2bf(v1.y), f2bf(v1.z), f2bf(v1.w)};
    }
  }

  float m_run[4], l_run[4];
  #pragma unroll
  for (int r = 0; r < 4; ++r) { m_run[r] = -INFINITY; l_run[r] = 0.f; }
  f32x4 oacc[6];
  #pragma unroll
  for (int ct = 0; ct < 6; ++ct) oacc[ct] = (f32x4)(0.f);

  const int kr = tid >> 2;
  const int cc = (tid & 3) * 24;

  for (int t = 0; t < LSEQ / 64; ++t) {
    const int k0 = t * 64;
    __syncthreads();
    {
      const float* kp = qkv + ((size_t)(b_ * LSEQ) + k0 + kr) * 2304 + DMODEL + h * HDIM + cc;
      const float* vp = kp + DMODEL;
      #pragma unroll
      for (int u = 0; u < 6; ++u) {
        float4 kv = *(const float4*)(kp + u * 4);
        *(short4_t*)&Ks[kr][cc + u * 4] =
            short4_t{f2bf(kv.x), f2bf(kv.y), f2bf(kv.z), f2bf(kv.w)};
        float4 vv = *(const float4*)(vp + u * 4);
        Vt[cc + u * 4 + 0][kr] = f2bf(vv.x);
        Vt[cc + u * 4 + 1][kr] = f2bf(vv.y);
        Vt[cc + u * 4 + 2][kr] = f2bf(vv.z);
        Vt[cc + u * 4 + 3][kr] = f2bf(vv.w);
      }
    }
    __syncthreads();

    f32x4 sacc[4];
    #pragma unroll
    for (int kt = 0; kt < 4; ++kt) sacc[kt] = (f32x4)(0.f);
    #pragma unroll
    for (int c = 0; c < 3; ++c) {
      #pragma unroll
      for (int kt = 0; kt < 4; ++kt) {
        short8 bfrag = *(const short8*)&Ks[kt * 16 + m16][c * 32 + g4 * 8];
        sacc[kt] = __builtin_amdgcn_mfma_f32_16x16x32_bf16(qf[c], bfrag, sacc[kt], 0, 0, 0);
      }
    }

    #pragma unroll
    for (int r = 0; r < 4; ++r) {
      float s0 = sacc[0][r] * sc2, s1 = sacc[1][r] * sc2;
      float s2v = sacc[2][r] * sc2, s3 = sacc[3][r] * sc2;
      float mv = fmaxf(fmaxf(s0, s1), fmaxf(s2v, s3));
      mv = fmaxf(mv, __shfl_xor(mv, 1));
      mv = fmaxf(mv, __shfl_xor(mv, 2));
      mv = fmaxf(mv, __shfl_xor(mv, 4));
      mv = fmaxf(mv, __shfl_xor(mv, 8));
      float mnew = fmaxf(m_run[r], mv);
      float scale = exp2f(m_run[r] - mnew);
      float p0 = exp2f(s0 - mnew), p1 = exp2f(s1 - mnew);
      float p2 = exp2f(s2v - mnew), p3 = exp2f(s3 - mnew);
      short* pr = &Ps[w][g4 * 4 + r][m16];
      pr[0]  = f2bf(p0);
      pr[16] = f2bf(p1);
      pr[32] = f2bf(p2);
      pr[48] = f2bf(p3);
      float ps = p0 + p1 + p2 + p3;
      ps += __shfl_xor(ps, 1);
      ps += __shfl_xor(ps, 2);
      ps += __shfl_xor(ps, 4);
      ps += __shfl_xor(ps, 8);
      l_run[r] = l_run[r] * scale + ps;
      m_run[r] = mnew;
      #pragma unroll
      for (int ct = 0; ct < 6; ++ct) oacc[ct][r] *= scale;
    }

    #pragma unroll
    for (int kc = 0; kc < 2; ++kc) {
      short8 pa = *(const short8*)&Ps[w][m16][kc * 32 + g4 * 8];
      #pragma unroll
      for (int ct = 0; ct < 6; ++ct) {
        short8 vb = *(const short8*)&Vt[ct * 16 + m16][kc * 32 + g4 * 8];
        oacc[ct] = __builtin_amdgcn_mfma_f32_16x16x32_bf16(pa, vb, oacc[ct], 0, 0, 0);
      }
    }
  }

  #pragma unroll
  for (int r = 0; r < 4; ++r) {
    float inv = 1.f / l_run[r];
    float* orow = o + ((size_t)(b_ * LSEQ) + q0 + w * 16 + g4 * 4 + r) * DMODEL + h * HDIM;
    #pragma unroll
    for (int ct = 0; ct < 6; ++ct)
      orow[ct * 16 + m16] = oacc[ct][r] * inv;
  }
}

// ---------------------------------------------------------------------------
// GLCE convs (kernels 3/5/7, 3 in-ch per out-ch, exact gelu)
// ---------------------------------------------------------------------------
__global__ __launch_bounds__(256) void glce_conv(
    const float* __restrict__ x,
    const float* __restrict__ w3, const float* __restrict__ b3,
    const float* __restrict__ w5, const float* __restrict__ b5,
    const float* __restrict__ w7, const float* __restrict__ b7,
    float* __restrict__ loc)
{
  int idx = blockIdx.x * 256 + threadIdx.x;
  int c = idx % DMODEL;
  int bl = idx / DMODEL;
  int l = bl & 1023, b_ = bl >> 10;
  int cs = c >> 8, ch = c & 255;
  const float* wp; float bias; int kt, pad;
  if (cs == 0)      { wp = w3 + ch * 9;  bias = b3[ch]; kt = 3; pad = 1; }
  else if (cs == 1) { wp = w5 + ch * 15; bias = b5[ch]; kt = 5; pad = 2; }
  else              { wp = w7 + ch * 21; bias = b7[ch]; kt = 7; pad = 3; }
  float acc = bias;
  const float* xb = x + (size_t)(b_ * LSEQ) * DMODEL;
  for (int i = 0; i < 3; ++i) {
    int d = 3 * ch + i;
    for (int t = 0; t < kt; ++t) {
      int ls = l - pad + t;
      if (ls >= 0 && ls < LSEQ)
        acc = fmaf(xb[(size_t)ls * DMODEL + d], wp[i * kt + t], acc);
    }
  }
  loc[idx] = 0.5f * acc * (1.f + erff(acc * 0.7071067811865475f));
}

// ---------------------------------------------------------------------------
// Mamba depthwise causal conv (K=4) + silu
// ---------------------------------------------------------------------------
__global__ __launch_bounds__(256) void mamba_conv_f32(
    const float* __restrict__ xiz, const float* __restrict__ cw,
    const float* __restrict__ cb, float* __restrict__ xc)
{
  int idx = blockIdx.x * 256 + threadIdx.x;
  int d = idx % DI_;
  int bl = idx / DI_;
  int l = bl & 1023, b_ = bl >> 10;
  const float* w = cw + d * 4;
  float acc = cb[d];
  #pragma unroll
  for (int t = 0; t < 4; ++t) {
    int ls = l - 3 + t;
    if (ls >= 0)
      acc = fmaf(xiz[((size_t)(b_ * LSEQ + ls)) * 3072 + d], w[t], acc);
  }
  xc[idx] = acc / (1.f + __expf(-acc));
}

// ---------------------------------------------------------------------------
// Chunked selective scan. CHUNK=64, NCHUNK=16.
// ---------------------------------------------------------------------------
__global__ __launch_bounds__(256) void mamba_scan_part(
    const float* __restrict__ dbc, const float* __restrict__ delta,
    const float* __restrict__ xc, const float* __restrict__ A_log,
    float* __restrict__ SS, float* __restrict__ PP)
{
  const int bc = blockIdx.x;
  const int b_ = bc / (96 * 16);
  const int rem = bc % (96 * 16);
  const int d0 = (rem >> 4) << 4;
  const int ck = rem & 15;
  const int tid = threadIdx.x;
  const int dl = tid >> 4, n = tid & 15;
  const int d = d0 + dl;
  const float a2 = -__expf(A_log[d * 16 + n]) * 1.4426950408889634f;

  __shared__ float sdel[64][16];
  __shared__ float sxc[64][16];
  __shared__ float sB[64][16];
  const size_t rowb = (size_t)b_ * LSEQ + ck * 64;

  #pragma unroll
  for (int k = 0; k < 4; ++k) {
    int i = tid + k * 256;
    int lc = i >> 4, c = i & 15;
    size_t row = rowb + lc;
    sdel[lc][c] = delta[row * 1536 + d0 + c];
    sxc[lc][c]  = xc[row * 1536 + d0 + c];
    sB[lc][c]   = dbc[row * 80 + 48 + c];
  }
  __syncthreads();

  float h = 0.f, sumd = 0.f;
  for (int lc = 0; lc < 64; ++lc) {
    float dlv = sdel[lc][dl];
    float xv  = sxc[lc][dl];
    float dA = exp2f(dlv * a2);
    h = fmaf(dA, h, dlv * xv * sB[lc][n]);
    sumd += dlv;
  }
  size_t idx = (((size_t)b_ * 1536 + d) * 16 + ck) * 16 + n;
  SS[idx] = h;
  PP[idx] = exp2f(a2 * sumd);
}

__global__ __launch_bounds__(256) void mamba_scan_comb(
    const float* __restrict__ SS, const float* __restrict__ PP,
    float* __restrict__ HI)
{
  int t = blockIdx.x * 256 + threadIdx.x;       // 0 .. 49151 = (b*1536+d)*16+n
  size_t base = (size_t)(t >> 4) * 256 + (t & 15);
  float run = 0.f;
  #pragma unroll
  for (int c = 0; c < 16; ++c) {
    size_t idx = base + c * 16;
    HI[idx] = run;
    run = fmaf(PP[idx], run, SS[idx]);
  }
}

__global__ __launch_bounds__(256) void mamba_scan_fin(
    const float* __restrict__ dbc, const float* __restrict__ delta,
    const float* __restrict__ xc, const float* __restrict__ xiz,
    const float* __restrict__ A_log, const float* __restrict__ Dp,
    const float* __restrict__ HI, float* __restrict__ yg)
{
  const int bc = blockIdx.x;
  const int b_ = bc / (96 * 16);
  const int rem = bc % (96 * 16);
  const int d0 = (rem >> 4) << 4;
  const int ck = rem & 15;
  const int tid = threadIdx.x;
  const int dl = tid >> 4, n = tid & 15;
  const int d = d0 + dl;
  const float a2 = -__expf(A_log[d * 16 + n]) * 1.4426950408889634f;
  const float dv = Dp[d];

  __shared__ float sdel[64][16];
  __shared__ float sxc[64][16];
  __shared__ float sz[64][16];
  __shared__ float sB[64][16];
  __shared__ float sC[64][16];
  __shared__ float sy[64][16];
  const size_t rowb = (size_t)b_ * LSEQ + ck * 64;

  #pragma unroll
  for (int k = 0; k < 4; ++k) {
    int i = tid + k * 256;
    int lc = i >> 4, c = i & 15;
    size_t row = rowb + lc;
    sdel[lc][c] = delta[row * 1536 + d0 + c];
    sxc[lc][c]  = xc[row * 1536 + d0 + c];
    sz[lc][c]   = xiz[row * 3072 + 1536 + d0 + c];
    sB[lc][c]   = dbc[row * 80 + 48 + c];
    sC[lc][c]   = dbc[row * 80 + 64 + c];
  }
  __syncthreads();

  float h = HI[(((size_t)b_ * 1536 + d) * 16 + ck) * 16 + n];
  for (int lc = 0; lc < 64; ++lc) {
    float dlv = sdel[lc][dl];
    float xv  = sxc[lc][dl];
    float dA = exp2f(dlv * a2);
    h = fmaf(dA, h, dlv * xv * sB[lc][n]);
    float p = h * sC[lc][n];
    p += __shfl_xor(p, 1);
    p += __shfl_xor(p, 2);
    p += __shfl_xor(p, 4);
    p += __shfl_xor(p, 8);
    if (n == 0) {
      float zv = sz[lc][dl];
      float y = p + xv * dv;
      sy[lc][dl] = y * (zv / (1.f + __expf(-zv)));
    }
  }
  __syncthreads();
  #pragma unroll
  for (int k = 0; k < 4; ++k) {
    int i = tid + k * 256;
    int lc = i >> 4, c = i & 15;
    yg[(rowb + lc) * 1536 + d0 + c] = sy[lc][c];
  }
}

// ---------------------------------------------------------------------------
// LayerNorm over last dim (768)
// ---------------------------------------------------------------------------
__global__ __launch_bounds__(256) void ln_f32(
    const float* __restrict__ in, const float* __restrict__ g,
    const float* __restrict__ b, float* __restrict__ out)
{
  int row = blockIdx.x * 4 + (threadIdx.x >> 6);
  int lane = threadIdx.x & 63;
  const float* xr = in + (size_t)row * DMODEL;
  float v[12];
  float s = 0.f, s2 = 0.f;
  #pragma unroll
  for (int i = 0; i < 12; ++i) {
    float t = xr[i * 64 + lane];
    v[i] = t; s += t; s2 = fmaf(t, t, s2);
  }
  #pragma unroll
  for (int off = 1; off < 64; off <<= 1) {
    s += __shfl_xor(s, off);
    s2 += __shfl_xor(s2, off);
  }
  float mean = s * (1.f / 768.f);
  float var = s2 * (1.f / 768.f) - mean * mean;
  float inv = rsqrtf(var + 1e-5f);
  float* orow = out + (size_t)row * DMODEL;
  #pragma unroll
  for (int i = 0; i < 12; ++i) {
    int c = i * 64 + lane;
    orow[c] = (v[i] - mean) * inv * g[c] + b[c];
  }
}

__global__ __launch_bounds__(256) void add3_f32(
    const float* __restrict__ a, const float* __restrict__ b,
    const float* __restrict__ c, float* __restrict__ o)
{
  int i = blockIdx.x * 256 + threadIdx.x;
  o[i] = a[i] + b[i] + c[i];
}

// ---------------------------------------------------------------------------
extern "C" void kernel_launch(void* const* d_in, const int* in_sizes, int n_in,
                              void* d_out, int out_size, void* d_ws, size_t ws_size,
                              hipStream_t stream)
{
  (void)in_sizes; (void)n_in; (void)out_size; (void)ws_size;
  const float* x         = (const float*)d_in[0];
  const float* qkv_w     = (const float*)d_in[1];
  const float* qkv_b     = (const float*)d_in[2];
  const float* att_out_w = (const float*)d_in[3];
  const float* att_out_b = (const float*)d_in[4];
  const float* conv3_w   = (const float*)d_in[5];
  const float* conv3_b   = (const float*)d_in[6];
  const float* conv5_w   = (const float*)d_in[7];
  const float* conv5_b   = (const float*)d_in[8];
  const float* conv7_w   = (const float*)d_in[9];
  const float* conv7_b   = (const float*)d_in[10];
  const float* gproj_w   = (const float*)d_in[11];
  const float* gproj_b   = (const float*)d_in[12];
  const float* lproj_w   = (const float*)d_in[13];
  const float* lproj_b   = (const float*)d_in[14];
  const float* fus_w     = (const float*)d_in[15];
  const float* fus_b     = (const float*)d_in[16];
  const float* glce_g    = (const float*)d_in[17];
  const float* glce_bb   = (const float*)d_in[18];
  const float* ssm_g     = (const float*)d_in[19];
  const float* ssm_bb    = (const float*)d_in[20];
  const float* in_w[2]   = {(const float*)d_in[21], (const float*)d_in[30]};
  const float* cw[2]     = {(const float*)d_in[22], (const float*)d_in[31]};
  const float* cb[2]     = {(const float*)d_in[23], (const float*)d_in[32]};
  const float* xp_w[2]   = {(const float*)d_in[24], (const float*)d_in[33]};
  const float* dt_w[2]   = {(const float*)d_in[25], (const float*)d_in[34]};
  const float* dt_b[2]   = {(const float*)d_in[26], (const float*)d_in[35]};
  const float* A_log[2]  = {(const float*)d_in[27], (const float*)d_in[36]};
  const float* Dp[2]     = {(const float*)d_in[28], (const float*)d_in[37]};
  const float* out_w[2]  = {(const float*)d_in[29], (const float*)d_in[38]};
  const float* ffn_g     = (const float*)d_in[39];
  const float* ffn_bb    = (const float*)d_in[40];
  const float* gate_w    = (const float*)d_in[41];
  const float* up_w      = (const float*)d_in[42];
  const float* down_w    = (const float*)d_in[43];

  float* ws = (float*)d_ws;
  size_t off = 0;
  const size_t M = 2048;
  auto take = [&](size_t n) { float* p = ws + off; off += n; return p; };
  float* QKV   = take(M * 2304);
  float* AO    = take(M * 768);
  float* AO2   = take(M * 768);
  float* GL    = take(M * 768);
  float* LOC   = take(M * 768);
  float* T1    = take(M * 768);
  float* X1    = take(M * 768);
  float* XN    = take(M * 768);
  float* XIZ   = take(M * 3072);
  float* XC    = take(M * 1536);
  float* DBC   = take(M * 80);
  float* DELTA = take(M * 1536);
  float* YG    = take(M * 1536);
  float* YF    = take(M * 768);
  float* YB    = take(M * 768);
  float* X2    = take(M * 768);
  float* SS    = take(2 * 1536 * 16 * 16);
  float* PP    = take(2 * 1536 * 16 * 16);
  float* HI    = take(2 * 1536 * 16 * 16);
  float* PART  = take((size_t)XP_KSPLIT * M * 80);
  float* GU    = XIZ;  // reuse (mamba finished before FFN)
  float* YFB[2] = {YF, YB};

  dim3 blk(256);

  // --- GLCE branch ---
  gemm_bf16<<<dim3(36, 32), blk, 0, stream>>>(x, 768, 0, qkv_w, qkv_b, nullptr,
                                              QKV, 2304, 0, 0, 2304, 768, 0, 0);
  attn_mfma<<<dim3(16, 16), blk, 0, stream>>>(QKV, AO);
  gemm_bf16<<<dim3(12, 32), blk, 0, stream>>>(AO, 768, 0, att_out_w, att_out_b, nullptr,
                                              AO2, 768, 0, 0, 768, 768, 0, 0);
  gemm_bf16<<<dim3(6, 32), blk, 0, stream>>>(AO2, 768, 0, gproj_w, gproj_b, nullptr,
                                             GL, 768, 0, 0, 384, 768, 0, 0);
  glce_conv<<<dim3(M * 768 / 256), blk, 0, stream>>>(x, conv3_w, conv3_b, conv5_w,
                                                     conv5_b, conv7_w, conv7_b, LOC);
  gemm_bf16<<<dim3(6, 32), blk, 0, stream>>>(LOC, 768, 0, lproj_w, lproj_b, nullptr,
                                             GL, 768, 384, 0, 384, 768, 0, 0);
  gemm_bf16<<<dim3(12, 32), blk, 0, stream>>>(GL, 768, 0, fus_w, fus_b, x,
                                              T1, 768, 0, 0, 768, 768, 0, 0);
  ln_f32<<<dim3(512), blk, 0, stream>>>(T1, glce_g, glce_bb, X1);

  // --- bidirectional mamba ---
  ln_f32<<<dim3(512), blk, 0, stream>>>(X1, ssm_g, ssm_bb, XN);
  for (int dir = 0; dir < 2; ++dir) {
    int flip = dir;
    gemm_bf16<<<dim3(48, 32), blk, 0, stream>>>(XN, 768, flip, in_w[dir], nullptr, nullptr,
                                                XIZ, 3072, 0, 0, 3072, 768, 0, 0);
    mamba_conv_f32<<<dim3(M * 1536 / 256), blk, 0, stream>>>(XIZ, cw[dir], cb[dir], XC);
    xp_part<<<dim3(32, XP_KSPLIT), blk, 0, stream>>>(XC, xp_w[dir], PART);
    xp_reduce<<<dim3(M * 80 / 256), blk, 0, stream>>>(PART, DBC);
    gemm_f32<<<dim3(24, 32), blk, 0, stream>>>(DBC, 80, 0, dt_w[dir], dt_b[dir], nullptr,
                                               DELTA, 1536, 0, 0, 1536, 48, 1, 0);
    mamba_scan_part<<<dim3(3072), blk, 0, stream>>>(DBC, DELTA, XC, A_log[dir], SS, PP);
    mamba_scan_comb<<<dim3(192), blk, 0, stream>>>(SS, PP, HI);
    mamba_scan_fin<<<dim3(3072), blk, 0, stream>>>(DBC, DELTA, XC, XIZ, A_log[dir],
                                                   Dp[dir], HI, YG);
    gemm_bf16<<<dim3(12, 32), blk, 0, stream>>>(YG, 1536, 0, out_w[dir], nullptr, nullptr,
                                                YFB[dir], 768, 0, flip, 768, 1536, 0, 0);
  }
  add3_f32<<<dim3(M * 768 / 256), blk, 0, stream>>>(X1, YF, YB, X2);

  // --- FFN ---
  ln_f32<<<dim3(512), blk, 0, stream>>>(X2, ffn_g, ffn_bb, XN);
  gemm_bf16<<<dim3(48, 32), blk, 0, stream>>>(XN, 768, 0, gate_w, nullptr, nullptr,
                                              GU, 3072, 0, 0, 3072, 768, 2, 0);
  gemm_bf16<<<dim3(48, 32), blk, 0, stream>>>(XN, 768, 0, up_w, nullptr, nullptr,
                                              GU, 3072, 0, 0, 3072, 768, 0, 1);
  gemm_bf16<<<dim3(12, 32), blk, 0, stream>>>(GU, 3072, 0, down_w, nullptr, X2,
                                              (float*)d_out, 768, 0, 0, 768, 3072, 0, 0);
}